// Round 10
// baseline (2158.673 us; speedup 1.0000x reference)
//
#include <hip/hip_runtime.h>
#include <hip/hip_bf16.h>

typedef __bf16  bf16x8 __attribute__((ext_vector_type(8)));
typedef float   f32x4  __attribute__((ext_vector_type(4)));

__device__ __constant__ int EDGE_A[19] = {1,8,9,1,11,12,1,2,3,2,1,5,6,5,0,0,0,14,15};
__device__ __constant__ int EDGE_B[19] = {8,9,10,11,12,13,2,3,4,16,5,6,7,17,1,14,15,16,17};

__device__ __forceinline__ unsigned short f2bf(float f) {
    unsigned int x = __float_as_uint(f);
    x += 0x7FFFu + ((x >> 16) & 1u);
    return (unsigned short)(x >> 16);
}

// packed fp32x2 -> bf16x2 (v_cvt_pk_bf16_f32), RNE
__device__ __forceinline__ unsigned int pack2(float a, float b) {
    __hip_bfloat162 t = __float22bfloat162_rn(make_float2(a, b));
    unsigned int r; __builtin_memcpy(&r, &t, 4); return r;
}

__device__ __forceinline__ void store_relu4(unsigned char* dst, f32x4 a, float4 b, bool oob) {
    unsigned int lo = pack2(fmaxf(a[0] + b.x, 0.f), fmaxf(a[1] + b.y, 0.f));
    unsigned int hi = pack2(fmaxf(a[2] + b.z, 0.f), fmaxf(a[3] + b.w, 0.f));
    uint2 v; v.x = oob ? 0u : lo; v.y = oob ? 0u : hi;
    *(uint2*)dst = v;
}

// ---------------------------------------------------------------------------
// Weight pre-pass (R8 layout, elem offsets in ws):
//   W1 @0     : 13tp x 16n x 32k            6656  (k=h*16+ic, t=2tp+h)
//   W2 @6656  : 13tp x 2nt x 16 x 32       13312
//   W3 @19968 : 25tap x 2nt x 16 x 32      25600  (k=ic)
//   W4 @45568 : 25 x 2 x 16 x 32           25600
//   W5 @71168 : 8nt x 16 x 32               4096
//   W0 @75264 : 4c x 16 x 32                2048  (k=tl*4+ic, t=c*8+tl)
// ---------------------------------------------------------------------------
extern "C" __global__ void __launch_bounds__(256)
reorder_weights(const float* __restrict__ w0, const float* __restrict__ w1,
                const float* __restrict__ w2, const float* __restrict__ w3,
                const float* __restrict__ w4, const float* __restrict__ w5,
                unsigned short* __restrict__ ws)
{
    int idx = blockIdx.x * 256 + threadIdx.x;
    if (idx < 6656) {
        int k = idx & 31, n = (idx >> 5) & 15, tp = idx >> 9;
        int t = 2 * tp + (k >> 4), ic = k & 15;
        float v = (t < 25) ? w1[(n * 16 + ic) * 25 + t] : 0.f;
        ws[idx] = f2bf(v);
    } else if (idx < 19968) {
        int j = idx - 6656;
        int k = j & 31, n = (j >> 5) & 15, nt = (j >> 9) & 1, tp = j >> 10;
        int t = 2 * tp + (k >> 4), ic = k & 15, oc = nt * 16 + n;
        float v = (t < 25) ? w2[(oc * 16 + ic) * 25 + t] : 0.f;
        ws[idx] = f2bf(v);
    } else if (idx < 45568) {
        int j = idx - 19968;
        int k = j & 31, n = (j >> 5) & 15, nt = (j >> 9) & 1, tap = j >> 10;
        ws[idx] = f2bf(w3[((nt * 16 + n) * 32 + k) * 25 + tap]);
    } else if (idx < 71168) {
        int j = idx - 45568;
        int k = j & 31, n = (j >> 5) & 15, nt = (j >> 9) & 1, tap = j >> 10;
        ws[idx] = f2bf(w4[((nt * 16 + n) * 32 + k) * 25 + tap]);
    } else if (idx < 75264) {
        int j = idx - 71168;
        int k = j & 31, oc = j >> 5;
        ws[idx] = f2bf(w5[oc * 32 + k]);
    } else if (idx < 77312) {
        int j = idx - 75264;
        int k = j & 31, n = (j >> 5) & 15, c = j >> 9;
        int t = c * 8 + (k >> 2), ic = k & 3;
        float v = (t < 25) ? w0[(n * 4 + ic) * 25 + t] : 0.f;
        ws[idx] = f2bf(v);
    }
}

// ---------------------------------------------------------------------------
// K-granule-major LDS layout: buffer = [g planes][pixel][16B], plane stride
// PSI/PSO bytes (= NPX*16 + 32 pad). Each quad's 16 lanes read 256 B
// contiguous -> conflict-free b128, no swizzle VALU.
// Paired-tap CIN=16 stage: quad -> (tap parity h = quad>>1, ch-granule
// g = quad&1). 8 waves, stride-8 mtiles.
// ---------------------------------------------------------------------------
template<int SIN, int SOUT, int NT, int MAXM, bool GUARD, int CH, int PSI, int PSO>
__device__ __forceinline__ void conv_p16k(
    const unsigned char* __restrict__ sinB, unsigned char* __restrict__ soutB,
    const unsigned short* __restrict__ wA, const float* __restrict__ bias,
    int gy0, int gx0, int wave, int lane)
{
    constexpr int NM = (SOUT * SOUT) / 16;
    const int nl = lane & 15, quad = lane >> 4;
    const int h = quad >> 1;
    const int gbase = (quad & 1) * PSI;

    int apx[MAXM];
#pragma unroll
    for (int i = 0; i < MAXM; ++i) {
        int mt = wave + 8 * i;
        if (!GUARD || mt < NM) {
            int p = mt * 16 + nl;
            int y = p / SOUT, x = p - y * SOUT;
            apx[i] = (y * SIN + x) * 16 + gbase;
        }
    }
    f32x4 acc[MAXM][NT];
#pragma unroll
    for (int i = 0; i < MAXM; ++i)
#pragma unroll
        for (int nt = 0; nt < NT; ++nt) acc[i][nt] = (f32x4)0.f;

    const unsigned short* wp = wA + nl * 32 + quad * 8;

#pragma unroll 1
    for (int c0 = 0; c0 < 13; c0 += CH) {
        bf16x8 wf[CH][NT];
#pragma unroll
        for (int tp = 0; tp < CH; ++tp)
            if (c0 + tp < 13)
#pragma unroll
                for (int nt = 0; nt < NT; ++nt)
                    wf[tp][nt] = *(const bf16x8*)(wp + ((c0 + tp) * NT + nt) * 512);
#pragma unroll
        for (int tp = 0; tp < CH; ++tp) {
            if (c0 + tp < 13) {
                int t = 2 * (c0 + tp) + h;
                if (t > 24) t = 24;              // padded half; weights zero
                int dy = t / 5, dx = t - 5 * dy;
                int toff = (dy * SIN + dx) * 16;
#pragma unroll
                for (int i = 0; i < MAXM; ++i)
                    if (!GUARD || wave + 8 * i < NM) {
                        bf16x8 a = *(const bf16x8*)(sinB + apx[i] + toff);
#pragma unroll
                        for (int nt = 0; nt < NT; ++nt)
                            acc[i][nt] = __builtin_amdgcn_mfma_f32_16x16x32_bf16(wf[tp][nt], a, acc[i][nt], 0, 0, 0);
                    }
            }
        }
    }

#pragma unroll
    for (int i = 0; i < MAXM; ++i) {
        int mt = wave + 8 * i;
        if (!GUARD || mt < NM) {
            int p = mt * 16 + nl;
            int y = p / SOUT, x = p - y * SOUT;
            bool oob = ((unsigned)(gy0 + y) >= 128u) || ((unsigned)(gx0 + x) >= 128u);
#pragma unroll
            for (int nt = 0; nt < NT; ++nt) {
                float4 bb = *(const float4*)(bias + nt * 16 + quad * 4);
                unsigned char* dst = soutB + (nt * 2 + (quad >> 1)) * PSO + p * 16 + (quad & 1) * 8;
                store_relu4(dst, acc[i][nt], bb, oob);
            }
        }
    }
}

// ---------------------------------------------------------------------------
// CIN=32 stage (K=32=ic), k-granule-major: quad = ch-granule. NT=2 fused.
// ---------------------------------------------------------------------------
template<int SIN, int SOUT, int MAXM, bool GUARD, int CH, int PSI, int PSO>
__device__ __forceinline__ void conv_c32k(
    const unsigned char* __restrict__ sinB, unsigned char* __restrict__ soutB,
    const unsigned short* __restrict__ wA, const float* __restrict__ bias,
    int gy0, int gx0, int wave, int lane)
{
    constexpr int NM = (SOUT * SOUT) / 16;
    const int nl = lane & 15, quad = lane >> 4;
    const int gbase = quad * PSI;

    int apx[MAXM];
#pragma unroll
    for (int i = 0; i < MAXM; ++i) {
        int mt = wave + 8 * i;
        if (!GUARD || mt < NM) {
            int p = mt * 16 + nl;
            int y = p / SOUT, x = p - y * SOUT;
            apx[i] = (y * SIN + x) * 16 + gbase;
        }
    }
    f32x4 acc[MAXM][2];
#pragma unroll
    for (int i = 0; i < MAXM; ++i) { acc[i][0] = (f32x4)0.f; acc[i][1] = (f32x4)0.f; }

    const unsigned short* wp = wA + nl * 32 + quad * 8;

#pragma unroll 1
    for (int c0 = 0; c0 < 25; c0 += CH) {
        bf16x8 wf[CH][2];
#pragma unroll
        for (int tp = 0; tp < CH; ++tp)
            if (c0 + tp < 25) {
                wf[tp][0] = *(const bf16x8*)(wp + ((c0 + tp) * 2 + 0) * 512);
                wf[tp][1] = *(const bf16x8*)(wp + ((c0 + tp) * 2 + 1) * 512);
            }
#pragma unroll
        for (int tp = 0; tp < CH; ++tp) {
            if (c0 + tp < 25) {
                int t = c0 + tp;
                int dy = t / 5, dx = t - 5 * dy;
                int toff = (dy * SIN + dx) * 16;
#pragma unroll
                for (int i = 0; i < MAXM; ++i)
                    if (!GUARD || wave + 8 * i < NM) {
                        bf16x8 a = *(const bf16x8*)(sinB + apx[i] + toff);
                        acc[i][0] = __builtin_amdgcn_mfma_f32_16x16x32_bf16(wf[tp][0], a, acc[i][0], 0, 0, 0);
                        acc[i][1] = __builtin_amdgcn_mfma_f32_16x16x32_bf16(wf[tp][1], a, acc[i][1], 0, 0, 0);
                    }
            }
        }
    }

#pragma unroll
    for (int i = 0; i < MAXM; ++i) {
        int mt = wave + 8 * i;
        if (!GUARD || mt < NM) {
            int p = mt * 16 + nl;
            int y = p / SOUT, x = p - y * SOUT;
            bool oob = ((unsigned)(gy0 + y) >= 128u) || ((unsigned)(gx0 + x) >= 128u);
#pragma unroll
            for (int nt = 0; nt < 2; ++nt) {
                float4 bb = *(const float4*)(bias + nt * 16 + quad * 4);
                unsigned char* dst = soutB + (nt * 2 + (quad >> 1)) * PSO + p * 16 + (quad & 1) * 8;
                store_relu4(dst, acc[i][nt], bb, oob);
            }
        }
    }
}

// ---------------------------------------------------------------------------
// Fused pipeline: one 512-thread block (8 waves) = one 16x16 output tile.
// (512,2): 256-reg waves (spill-free) x 2 blocks/CU = 16 waves/CU.
// LDS 65536 B, k-granule-major planes (stride = NPX*16+32):
//   s_in@0 10368 | s0@32736 (2x16416) | s1@0 (2x12576=25120)
//   s2@25728 (4x9248) | s3@0 (4x6432=25696) | s4@32768 (4x4128)
// Schedule: gather|c0|c1|c2(NT2)|c3|c4|c5  (7 barriers)
// ---------------------------------------------------------------------------
extern "C" __global__ void __launch_bounds__(512, 2)
gnn_paf_mfma(const float* __restrict__ cnn, const unsigned short* __restrict__ wB,
             const float* __restrict__ b0, const float* __restrict__ b1,
             const float* __restrict__ b2, const float* __restrict__ b3,
             const float* __restrict__ b4, const float* __restrict__ b5,
             const float* __restrict__ w6, const float* __restrict__ b6,
             float* __restrict__ out)
{
    __shared__ __align__(64) unsigned char smem[65536];
    unsigned short* const s_in = (unsigned short*)smem;   // 1296 px x 8B
    unsigned char*  const s1   = smem;                    // 2 x 12576
    unsigned char*  const s3   = smem;                    // 4 x 6432
    unsigned char*  const s2   = smem + 25728;            // 4 x 9248
    unsigned char*  const s0   = smem + 32736;            // 2 x 16416
    unsigned char*  const s4   = smem + 32768;            // 4 x 4128

    const int tid  = threadIdx.x;
    const int lane = tid & 63, wave = tid >> 6;           // 8 waves
    const int tile = blockIdx.x, img = blockIdx.y;
    const int oy = (tile >> 3) * 16, ox = (tile & 7) * 16;
    const int n = img / 19, g = img - n * 19;
    const int ch0 = EDGE_A[g], ch1 = EDGE_B[g], ch2 = 19 + 2 * g, ch3 = 20 + 2 * g;
    const int nl = lane & 15, quad = lane >> 4;
    const long long nb = (long long)n * 57 * 16384;

    // ---- gather -> s_in bf16 HWC4 (36x36 halo, zero-padded)
    for (int idx = tid; idx < 1296; idx += 512) {
        int r = idx / 36, c = idx - r * 36;
        int gy = oy - 10 + r, gx = ox - 10 + c;
        float v0 = 0.f, v1 = 0.f, v2 = 0.f, v3 = 0.f;
        if ((unsigned)gy < 128u && (unsigned)gx < 128u) {
            int off = gy * 128 + gx;
            v0 = cnn[nb + (long long)ch0 * 16384 + off];
            v1 = cnn[nb + (long long)ch1 * 16384 + off];
            v2 = cnn[nb + (long long)ch2 * 16384 + off];
            v3 = cnn[nb + (long long)ch3 * 16384 + off];
        }
        uint2 v; v.x = pack2(v0, v1); v.y = pack2(v2, v3);
        *(uint2*)(s_in + idx * 4) = v;
    }
    __syncthreads();

    // ---- conv0 (4->16): K=32 = 8 taps x 4ch, 4 chunks; out k-granule-major
    {
        bf16x8 wf[4];
#pragma unroll
        for (int c = 0; c < 4; ++c)
            wf[c] = *(const bf16x8*)(wB + 75264 + c * 512 + nl * 32 + quad * 8);
        float4 bb = *(const float4*)(b0 + quad * 4);
#pragma unroll 1
        for (int i = 0; i < 8; ++i) {
            int mt = wave + 8 * i;                 // 64 mtiles (32x32 px)
            int p = mt * 16 + nl;
            int y = p >> 5, x = p & 31;
            f32x4 acc = (f32x4)0.f;
#pragma unroll
            for (int c = 0; c < 4; ++c) {
                int t0 = c * 8 + quad * 2, t1 = t0 + 1;
                if (t0 > 24) t0 = 24;
                if (t1 > 24) t1 = 24;              // padded taps; weights zero
                int dy0 = t0 / 5, dx0 = t0 - 5 * dy0;
                int dy1 = t1 / 5, dx1 = t1 - 5 * dy1;
                uint2 lo = *(const uint2*)(s_in + ((y + dy0) * 36 + x + dx0) * 4);
                uint2 hi = *(const uint2*)(s_in + ((y + dy1) * 36 + x + dx1) * 4);
                bf16x8 a;
                ((uint2*)&a)[0] = lo; ((uint2*)&a)[1] = hi;
                acc = __builtin_amdgcn_mfma_f32_16x16x32_bf16(wf[c], a, acc, 0, 0, 0);
            }
            bool oob = ((unsigned)(oy - 8 + y) >= 128u) || ((unsigned)(ox - 8 + x) >= 128u);
            unsigned char* dst = s0 + (quad >> 1) * 16416 + p * 16 + (quad & 1) * 8;
            store_relu4(dst, acc, bb, oob);
        }
    }
    __syncthreads();

    conv_p16k<32, 28, 1, 7, true, 5, 16416, 12576>(s0, s1, wB + 0,     b1, oy - 6, ox - 6, wave, lane);
    __syncthreads();
    conv_p16k<28, 24, 2, 5, true, 5, 12576, 9248>(s1, s2, wB + 6656,  b2, oy - 4, ox - 4, wave, lane);
    __syncthreads();
    conv_c32k<24, 20, 4, true, 5, 9248, 6432>(s2, s3, wB + 19968, b3, oy - 2, ox - 2, wave, lane);
    __syncthreads();
    conv_c32k<20, 16, 2, false, 5, 6432, 4128>(s3, s4, wB + 45568, b4, oy, ox, wave, lane);
    __syncthreads();

    // ---- conv5 (1x1 32->128) + relu + conv6 (128->2)
    {
        bf16x8 w5f[8];
#pragma unroll
        for (int nt = 0; nt < 8; ++nt)
            w5f[nt] = *(const bf16x8*)(wB + 71168 + nt * 512 + nl * 32 + quad * 8);
        const float b6q = b6[quad & 1];
#pragma unroll 1
        for (int ii = 0; ii < 2; ++ii) {
            int mt = wave + 8 * ii;                // 16 mtiles
            bf16x8 pf = *(const bf16x8*)(s4 + quad * 4128 + (mt * 16 + nl) * 16);
            float o0 = 0.f, o1 = 0.f;
#pragma unroll
            for (int nt = 0; nt < 8; ++nt) {
                f32x4 acc = (f32x4)0.f;
                acc = __builtin_amdgcn_mfma_f32_16x16x32_bf16(w5f[nt], pf, acc, 0, 0, 0);
                float4 bb  = *(const float4*)(b5 + nt * 16 + quad * 4);
                float4 wa  = *(const float4*)(w6 + nt * 16 + quad * 4);
                float4 wb2 = *(const float4*)(w6 + 128 + nt * 16 + quad * 4);
                float h0 = fmaxf(acc[0] + bb.x, 0.f), h1 = fmaxf(acc[1] + bb.y, 0.f);
                float h2 = fmaxf(acc[2] + bb.z, 0.f), h3 = fmaxf(acc[3] + bb.w, 0.f);
                o0 = fmaf(h0, wa.x, fmaf(h1, wa.y, fmaf(h2, wa.z, fmaf(h3, wa.w, o0))));
                o1 = fmaf(h0, wb2.x, fmaf(h1, wb2.y, fmaf(h2, wb2.z, fmaf(h3, wb2.w, o1))));
            }
            o0 += __shfl_xor(o0, 16, 64); o0 += __shfl_xor(o0, 32, 64);
            o1 += __shfl_xor(o1, 16, 64); o1 += __shfl_xor(o1, 32, 64);
            if (quad < 2) {
                float val = ((quad == 0) ? o0 : o1) + b6q;
                long long ob = (((long long)n * 38 + 2 * g + quad) * 128 + (oy + mt)) * 128 + (ox + nl);
                out[ob] = val;
            }
        }
    }
}

extern "C" void kernel_launch(void* const* d_in, const int* in_sizes, int n_in,
                              void* d_out, int out_size, void* d_ws, size_t ws_size,
                              hipStream_t stream) {
    const float* cnn = (const float*)d_in[0];
    const float* w0 = (const float*)d_in[2];  const float* b0 = (const float*)d_in[3];
    const float* w1 = (const float*)d_in[4];  const float* b1 = (const float*)d_in[5];
    const float* w2 = (const float*)d_in[6];  const float* b2 = (const float*)d_in[7];
    const float* w3 = (const float*)d_in[8];  const float* b3 = (const float*)d_in[9];
    const float* w4 = (const float*)d_in[10]; const float* b4 = (const float*)d_in[11];
    const float* w5 = (const float*)d_in[12]; const float* b5 = (const float*)d_in[13];
    const float* w6 = (const float*)d_in[14]; const float* b6 = (const float*)d_in[15];
    float* out = (float*)d_out;
    unsigned short* wB = (unsigned short*)d_ws;   // 154,624 B used

    hipLaunchKernelGGL(reorder_weights, dim3(302), dim3(256), 0, stream,
                       w0, w1, w2, w3, w4, w5, wB);
    hipLaunchKernelGGL(gnn_paf_mfma, dim3(64, 304), dim3(512), 0, stream,
                       cnn, wB, b0, b1, b2, b3, b4, b5, w6, b6, out);
}

// Round 11
// 1635.030 us; speedup vs baseline: 1.3203x; 1.3203x over previous
//
#include <hip/hip_runtime.h>
#include <hip/hip_bf16.h>

typedef __bf16  bf16x8 __attribute__((ext_vector_type(8)));
typedef float   f32x4  __attribute__((ext_vector_type(4)));

__device__ __constant__ int EDGE_A[19] = {1,8,9,1,11,12,1,2,3,2,1,5,6,5,0,0,0,14,15};
__device__ __constant__ int EDGE_B[19] = {8,9,10,11,12,13,2,3,4,16,5,6,7,17,1,14,15,16,17};

#define SINV (1.0f / 4096.0f)   // 1/(Sw*Sa), Sw=Sa=64
#define SACT 64.0f

__device__ __forceinline__ unsigned short f2bf(float f) {
    unsigned int x = __float_as_uint(f);
    x += 0x7FFFu + ((x >> 16) & 1u);
    return (unsigned short)(x >> 16);
}
__device__ __forceinline__ unsigned int pack2(float a, float b) {
    __hip_bfloat162 t = __float22bfloat162_rn(make_float2(a, b));
    unsigned int r; __builtin_memcpy(&r, &t, 4); return r;
}
__device__ __forceinline__ unsigned char f2fp8(float v) {
    int r = __builtin_amdgcn_cvt_pk_fp8_f32(v, 0.f, 0, false);
    return (unsigned char)(r & 0xff);
}
__device__ __forceinline__ unsigned int pk4fp8(float a, float b, float c, float d) {
    int v = __builtin_amdgcn_cvt_pk_fp8_f32(a, b, 0, false);
    v = __builtin_amdgcn_cvt_pk_fp8_f32(c, d, v, true);
    return (unsigned int)v;
}

// swizzles (granule-preserving XOR)
__device__ __forceinline__ int sw16(int l) { return l ^ ((l >> 3) & 16); }  // 32B rows, 16B units
__device__ __forceinline__ int sw8 (int l) { return l ^ ((l >> 4) & 8);  }  // 16B rows, 8B units
__device__ __forceinline__ int sw32(int l) { return l ^ ((l >> 5) & 24); }  // 32B rows, 8B units
__device__ __forceinline__ int sw48(int l) { return l ^ ((l >> 3) & 48); }  // 64B rows, 16B units

__device__ __forceinline__ void store_relu4(unsigned char* dst, f32x4 a, float4 b, bool oob) {
    unsigned int lo = pack2(fmaxf(a[0] + b.x, 0.f), fmaxf(a[1] + b.y, 0.f));
    unsigned int hi = pack2(fmaxf(a[2] + b.z, 0.f), fmaxf(a[3] + b.w, 0.f));
    uint2 v; v.x = oob ? 0u : lo; v.y = oob ? 0u : hi;
    *(uint2*)dst = v;
}

// ---------------------------------------------------------------------------
// Weight pre-pass, ws BYTE layout:
//   W1 bf16 @0     : 13tp x 16n x 32k shorts              (13312 B)
//   W5 bf16 @13312 : 8nt x 16 x 32 shorts                 ( 8192 B)
//   W0 bf16 @21504 : 4c x 16 x 32 shorts                  ( 4096 B)
//   W2 fp8  @25600 : 13tp x 2nt x 16n x 32k bytes, x64    (13312 B)
//   W3 fp8  @38912 : 25tap x 2nt x 16 x 32 (k=ic), x64    (25600 B)
//   W4 fp8  @64512 : 25tap x 2nt x 16 x 32 (k=ic), x64    (25600 B)
// total 90112 B
// ---------------------------------------------------------------------------
extern "C" __global__ void __launch_bounds__(256)
reorder_weights(const float* __restrict__ w0, const float* __restrict__ w1,
                const float* __restrict__ w2, const float* __restrict__ w3,
                const float* __restrict__ w4, const float* __restrict__ w5,
                unsigned char* __restrict__ ws)
{
    int idx = blockIdx.x * 256 + threadIdx.x;
    unsigned short* wsS = (unsigned short*)ws;
    if (idx < 6656) {                       // W1 (shorts 0..6655)
        int k = idx & 31, n = (idx >> 5) & 15, tp = idx >> 9;
        int t = 2 * tp + (k >> 4), ic = k & 15;
        float v = (t < 25) ? w1[(n * 16 + ic) * 25 + t] : 0.f;
        wsS[idx] = f2bf(v);
    } else if (idx < 10752) {               // W5
        int j = idx - 6656;
        int k = j & 31, oc = j >> 5;
        wsS[idx] = f2bf(w5[oc * 32 + k]);
    } else if (idx < 12800) {               // W0
        int j = idx - 10752;
        int k = j & 31, n = (j >> 5) & 15, c = j >> 9;
        int t = c * 8 + (k >> 2), ic = k & 3;
        float v = (t < 25) ? w0[(n * 4 + ic) * 25 + t] : 0.f;
        wsS[idx] = f2bf(v);
    }
    if (idx < 13312) {                      // W2 fp8
        int k = idx & 31, n = (idx >> 5) & 15, nt = (idx >> 9) & 1, tp = idx >> 10;
        int t = 2 * tp + (k >> 4), ic = k & 15, oc = nt * 16 + n;
        float v = (t < 25) ? w2[(oc * 16 + ic) * 25 + t] * SACT : 0.f;
        ws[25600 + idx] = f2fp8(v);
    } else if (idx < 38912) {               // W3 fp8
        int j = idx - 13312;
        int k = j & 31, n = (j >> 5) & 15, nt = (j >> 9) & 1, tap = j >> 10;
        ws[25600 + idx] = f2fp8(w3[((nt * 16 + n) * 32 + k) * 25 + tap] * SACT);
    } else if (idx < 64512) {               // W4 fp8
        int j = idx - 38912;
        int k = j & 31, n = (j >> 5) & 15, nt = (j >> 9) & 1, tap = j >> 10;
        ws[25600 + idx] = f2fp8(w4[((nt * 16 + n) * 32 + k) * 25 + tap] * SACT);
    }
}

// ---------------------------------------------------------------------------
// conv0 (4->16) bf16 on an 18-row slab: 36 mtiles; out s0 [px][32B] sw16.
// ---------------------------------------------------------------------------
__device__ __forceinline__ void conv0_slab(
    const unsigned short* __restrict__ s_in, unsigned char* __restrict__ s0,
    const unsigned char* __restrict__ wB, const float* __restrict__ b0,
    int yoff, int oy, int ox, int wave, int lane)
{
    const int nl = lane & 15, quad = lane >> 4;
    const unsigned short* w0p = (const unsigned short*)(wB + 21504);
    bf16x8 wf[4];
#pragma unroll
    for (int c = 0; c < 4; ++c)
        wf[c] = *(const bf16x8*)(w0p + c * 512 + nl * 32 + quad * 8);
    float4 bb = *(const float4*)(b0 + quad * 4);
#pragma unroll 1
    for (int i = 0; i < 9; ++i) {
        int mt = wave + 4 * i;
        int p = mt * 16 + nl;
        int y = p >> 5, x = p & 31;
        f32x4 acc = (f32x4)0.f;
#pragma unroll
        for (int c = 0; c < 4; ++c) {
            int t0 = c * 8 + quad * 2, t1 = t0 + 1;
            if (t0 > 24) t0 = 24;
            if (t1 > 24) t1 = 24;
            int dy0 = t0 / 5, dx0 = t0 - 5 * dy0;
            int dy1 = t1 / 5, dx1 = t1 - 5 * dy1;
            uint2 lo = *(const uint2*)(s_in + ((y + dy0) * 36 + x + dx0) * 4);
            uint2 hi = *(const uint2*)(s_in + ((y + dy1) * 36 + x + dx1) * 4);
            bf16x8 a;
            ((uint2*)&a)[0] = lo; ((uint2*)&a)[1] = hi;
            acc = __builtin_amdgcn_mfma_f32_16x16x32_bf16(wf[c], a, acc, 0, 0, 0);
        }
        bool oob = ((unsigned)(oy - 8 + y + yoff) >= 128u) || ((unsigned)(ox - 8 + x) >= 128u);
        store_relu4(s0 + sw16(p * 32 + quad * 8), acc, bb, oob);
    }
}

// ---------------------------------------------------------------------------
// conv1 half-slab: bf16 in (s0, 18 rows x 32 wide), fp8 x64 out (s1 16B rows).
// NPXL=392 (14 out rows of 28). Paired-tap, NT=1, MAXM=7.
// ---------------------------------------------------------------------------
__device__ __forceinline__ void conv1_half(
    const unsigned char* __restrict__ s0, unsigned char* __restrict__ s1,
    const unsigned char* __restrict__ wB, const float* __restrict__ b1,
    int POFF, int gy0, int gx0, int wave, int lane)
{
    const int nl = lane & 15, quad = lane >> 4;
    const int h = quad >> 1, coff = (quad & 1) * 16;

    int abase[7];
#pragma unroll
    for (int i = 0; i < 7; ++i) {
        int p = (wave + 4 * i) * 16 + nl;
        if (p > 391) p = 391;
        int y = p / 28, x = p - y * 28;
        abase[i] = (y * 32 + x) * 32 + coff;
    }
    f32x4 acc[7];
#pragma unroll
    for (int i = 0; i < 7; ++i) acc[i] = (f32x4)0.f;

    const unsigned short* wp = (const unsigned short*)(wB) + nl * 32 + quad * 8;

#pragma unroll 1
    for (int c0 = 0; c0 < 13; c0 += 5) {
        bf16x8 wf[5];
#pragma unroll
        for (int tp = 0; tp < 5; ++tp)
            if (c0 + tp < 13) wf[tp] = *(const bf16x8*)(wp + (c0 + tp) * 512);
#pragma unroll
        for (int tp = 0; tp < 5; ++tp) {
            if (c0 + tp < 13) {
                int t = 2 * (c0 + tp) + h;
                if (t > 24) t = 24;
                int dy = t / 5, dx = t - 5 * dy;
                int toff = (dy * 32 + dx) * 32;
#pragma unroll
                for (int i = 0; i < 7; ++i)
                    if (wave + 4 * i < 25) {
                        bf16x8 a = *(const bf16x8*)(s0 + sw16(abase[i] + toff));
                        acc[i] = __builtin_amdgcn_mfma_f32_16x16x32_bf16(wf[tp], a, acc[i], 0, 0, 0);
                    }
            }
        }
    }

    float4 bb = *(const float4*)(b1 + quad * 4);
#pragma unroll
    for (int i = 0; i < 7; ++i) {
        int p = (wave + 4 * i) * 16 + nl;
        if (p < 392) {
            int pg = p + POFF;
            int y = pg / 28, x = pg - y * 28;
            bool oob = ((unsigned)(gy0 + y) >= 128u) || ((unsigned)(gx0 + x) >= 128u);
            unsigned int v = pk4fp8(fmaxf(acc[i][0] + bb.x, 0.f) * SACT,
                                    fmaxf(acc[i][1] + bb.y, 0.f) * SACT,
                                    fmaxf(acc[i][2] + bb.z, 0.f) * SACT,
                                    fmaxf(acc[i][3] + bb.w, 0.f) * SACT);
            *(unsigned int*)(s1 + sw8(pg * 16 + quad * 4)) = oob ? 0u : v;
        }
    }
}

// ---------------------------------------------------------------------------
// conv2: fp8 paired-tap (CIN=16, K=32=2tp x 16ch), NT=2, single pass.
// in s1 [784px][16B] sw8, out s2 [576px][32B] sw32, fp8 x64.
// ---------------------------------------------------------------------------
__device__ __forceinline__ void conv2_fp8(
    const unsigned char* __restrict__ s1, unsigned char* __restrict__ s2,
    const unsigned char* __restrict__ wB, const float* __restrict__ b2,
    int gy0, int gx0, int wave, int lane)
{
    const int nl = lane & 15, quad = lane >> 4;
    const int h = quad >> 1, g8 = (quad & 1) * 8;

    int abase[9];
#pragma unroll
    for (int i = 0; i < 9; ++i) {
        int p = (wave + 4 * i) * 16 + nl;
        int y = p / 24, x = p - y * 24;
        abase[i] = (y * 28 + x) * 16 + g8;
    }
    f32x4 acc[9][2];
#pragma unroll
    for (int i = 0; i < 9; ++i) { acc[i][0] = (f32x4)0.f; acc[i][1] = (f32x4)0.f; }

    const unsigned char* wp = wB + 25600 + nl * 32 + quad * 8;

#pragma unroll 1
    for (int c0 = 0; c0 < 13; c0 += 3) {
        long wl[3][2];
#pragma unroll
        for (int tp = 0; tp < 3; ++tp)
            if (c0 + tp < 13) {
                wl[tp][0] = *(const long*)(wp + ((c0 + tp) * 2 + 0) * 512);
                wl[tp][1] = *(const long*)(wp + ((c0 + tp) * 2 + 1) * 512);
            }
#pragma unroll
        for (int tp = 0; tp < 3; ++tp) {
            if (c0 + tp < 13) {
                int t = 2 * (c0 + tp) + h;
                if (t > 24) t = 24;
                int dy = t / 5, dx = t - 5 * dy;
                int toff = (dy * 28 + dx) * 16;
#pragma unroll
                for (int i = 0; i < 9; ++i) {
                    long a = *(const long*)(s1 + sw8(abase[i] + toff));
                    acc[i][0] = __builtin_amdgcn_mfma_f32_16x16x32_fp8_fp8(wl[tp][0], a, acc[i][0], 0, 0, 0);
                    acc[i][1] = __builtin_amdgcn_mfma_f32_16x16x32_fp8_fp8(wl[tp][1], a, acc[i][1], 0, 0, 0);
                }
            }
        }
    }

#pragma unroll
    for (int i = 0; i < 9; ++i) {
        int p = (wave + 4 * i) * 16 + nl;
        int y = p / 24, x = p - y * 24;
        bool oob = ((unsigned)(gy0 + y) >= 128u) || ((unsigned)(gx0 + x) >= 128u);
#pragma unroll
        for (int nt = 0; nt < 2; ++nt) {
            float4 bb = *(const float4*)(b2 + nt * 16 + quad * 4);
            unsigned int v = pk4fp8(fmaxf(acc[i][nt][0] * SINV + bb.x, 0.f) * SACT,
                                    fmaxf(acc[i][nt][1] * SINV + bb.y, 0.f) * SACT,
                                    fmaxf(acc[i][nt][2] * SINV + bb.z, 0.f) * SACT,
                                    fmaxf(acc[i][nt][3] * SINV + bb.w, 0.f) * SACT);
            *(unsigned int*)(s2 + sw32(p * 32 + nt * 16 + quad * 4)) = oob ? 0u : v;
        }
    }
}

// ---------------------------------------------------------------------------
// conv3/conv4: fp8 25-tap (CIN=32, K=32=ic), NT=2, c32-style.
// FP8OUT: fp8 x64 to 32B rows (sw32); else bf16 to 64B rows (sw48).
// ---------------------------------------------------------------------------
template<int SIN, int SOUT, int MAXM, bool GUARD, bool FP8OUT>
__device__ __forceinline__ void conv_c32_fp8(
    const unsigned char* __restrict__ sinB, unsigned char* __restrict__ soutB,
    const unsigned char* __restrict__ wA, const float* __restrict__ bias,
    int gy0, int gx0, int wave, int lane)
{
    constexpr int NM = (SOUT * SOUT) / 16;
    const int nl = lane & 15, quad = lane >> 4;

    int abase[MAXM];
#pragma unroll
    for (int i = 0; i < MAXM; ++i) {
        int p = (wave + 4 * i) * 16 + nl;
        if (GUARD && p > SOUT * SOUT - 1) p = SOUT * SOUT - 1;
        int y = p / SOUT, x = p - y * SOUT;
        abase[i] = (y * SIN + x) * 32 + quad * 8;
    }
    f32x4 acc[MAXM][2];
#pragma unroll
    for (int i = 0; i < MAXM; ++i) { acc[i][0] = (f32x4)0.f; acc[i][1] = (f32x4)0.f; }

    const unsigned char* wp = wA + nl * 32 + quad * 8;

#pragma unroll 1
    for (int c0 = 0; c0 < 25; c0 += 5) {
        long wl[5][2];
#pragma unroll
        for (int tp = 0; tp < 5; ++tp) {
            wl[tp][0] = *(const long*)(wp + ((c0 + tp) * 2 + 0) * 512);
            wl[tp][1] = *(const long*)(wp + ((c0 + tp) * 2 + 1) * 512);
        }
#pragma unroll
        for (int tp = 0; tp < 5; ++tp) {
            int t = c0 + tp;
            int dy = t / 5, dx = t - 5 * dy;
            int toff = (dy * SIN + dx) * 32;
#pragma unroll
            for (int i = 0; i < MAXM; ++i)
                if (!GUARD || wave + 4 * i < NM) {
                    long a = *(const long*)(sinB + sw32(abase[i] + toff));
                    acc[i][0] = __builtin_amdgcn_mfma_f32_16x16x32_fp8_fp8(wl[tp][0], a, acc[i][0], 0, 0, 0);
                    acc[i][1] = __builtin_amdgcn_mfma_f32_16x16x32_fp8_fp8(wl[tp][1], a, acc[i][1], 0, 0, 0);
                }
        }
    }

#pragma unroll
    for (int i = 0; i < MAXM; ++i) {
        int p = (wave + 4 * i) * 16 + nl;
        if (!GUARD || p < SOUT * SOUT) {
            int y = p / SOUT, x = p - y * SOUT;
            bool oob = ((unsigned)(gy0 + y) >= 128u) || ((unsigned)(gx0 + x) >= 128u);
#pragma unroll
            for (int nt = 0; nt < 2; ++nt) {
                float4 bb = *(const float4*)(bias + nt * 16 + quad * 4);
                if (FP8OUT) {
                    unsigned int v = pk4fp8(fmaxf(acc[i][nt][0] * SINV + bb.x, 0.f) * SACT,
                                            fmaxf(acc[i][nt][1] * SINV + bb.y, 0.f) * SACT,
                                            fmaxf(acc[i][nt][2] * SINV + bb.z, 0.f) * SACT,
                                            fmaxf(acc[i][nt][3] * SINV + bb.w, 0.f) * SACT);
                    *(unsigned int*)(soutB + sw32(p * 32 + nt * 16 + quad * 4)) = oob ? 0u : v;
                } else {
                    f32x4 s;
                    s[0] = acc[i][nt][0] * SINV; s[1] = acc[i][nt][1] * SINV;
                    s[2] = acc[i][nt][2] * SINV; s[3] = acc[i][nt][3] * SINV;
                    store_relu4(soutB + sw48(p * 64 + nt * 32 + quad * 8), s, bb, oob);
                }
            }
        }
    }
}

// ---------------------------------------------------------------------------
// Fused pipeline, 4 blocks/CU target: 256 threads = one 16x16 output tile.
// LDS 37568 B: S1@0 12544 | S3@0 12800 | SIN@12800 6336 | S0/S2/S4@19136
// Schedule: gatherA|c0a|{c1a+gatherB}|c0b|c1b|c2|c3|c4|c5
// ---------------------------------------------------------------------------
extern "C" __global__ void __launch_bounds__(256, 4)
gnn_paf_mfma(const float* __restrict__ cnn, const unsigned char* __restrict__ wB,
             const float* __restrict__ b0, const float* __restrict__ b1,
             const float* __restrict__ b2, const float* __restrict__ b3,
             const float* __restrict__ b4, const float* __restrict__ b5,
             const float* __restrict__ w6, const float* __restrict__ b6,
             float* __restrict__ out)
{
    __shared__ __align__(64) unsigned char smem[37568];
    unsigned char*  const s1   = smem;                             // 12544
    unsigned char*  const s3   = smem;                             // 12800
    unsigned short* const sin_ = (unsigned short*)(smem + 12800);  // 6336
    unsigned char*  const s0   = smem + 19136;                     // 18432
    unsigned char*  const s2   = smem + 19136;                     // 18432
    unsigned char*  const s4   = smem + 19136;                     // 16384

    const int tid  = threadIdx.x;
    const int lane = tid & 63, wave = tid >> 6;       // 4 waves
    const int tile = blockIdx.x, img = blockIdx.y;
    const int oy = (tile >> 3) * 16, ox = (tile & 7) * 16;
    const int n = img / 19, g = img - n * 19;
    const int ch0 = EDGE_A[g], ch1 = EDGE_B[g], ch2 = 19 + 2 * g, ch3 = 20 + 2 * g;
    const int nl = lane & 15, quad = lane >> 4;
    const long long nb = (long long)n * 57 * 16384;

    // ---- gatherA: halo rows 0..21 -> sin_ (22x36x4 bf16, zero-padded)
    for (int idx = tid; idx < 792; idx += 256) {
        int r = idx / 36, c = idx - r * 36;
        int gy = oy - 10 + r, gx = ox - 10 + c;
        float v0 = 0.f, v1 = 0.f, v2 = 0.f, v3 = 0.f;
        if ((unsigned)gy < 128u && (unsigned)gx < 128u) {
            int off = gy * 128 + gx;
            v0 = cnn[nb + (long long)ch0 * 16384 + off];
            v1 = cnn[nb + (long long)ch1 * 16384 + off];
            v2 = cnn[nb + (long long)ch2 * 16384 + off];
            v3 = cnn[nb + (long long)ch3 * 16384 + off];
        }
        uint2 v; v.x = pack2(v0, v1); v.y = pack2(v2, v3);
        *(uint2*)(sin_ + idx * 4) = v;
    }
    __syncthreads();

    conv0_slab(sin_, s0, wB, b0, 0, oy, ox, wave, lane);       // s0 rows 0..17
    __syncthreads();

    // gatherB loads (input rows 14..35) pipelined across conv1a
    float gv[4][4];
#pragma unroll
    for (int j = 0; j < 4; ++j) {
        gv[j][0] = gv[j][1] = gv[j][2] = gv[j][3] = 0.f;
        int idx = tid + 256 * j;
        if (idx < 792) {
            int r = idx / 36, c = idx - r * 36;
            int gy = oy + 4 + r, gx = ox - 10 + c;
            if ((unsigned)gy < 128u && (unsigned)gx < 128u) {
                int off = gy * 128 + gx;
                gv[j][0] = cnn[nb + (long long)ch0 * 16384 + off];
                gv[j][1] = cnn[nb + (long long)ch1 * 16384 + off];
                gv[j][2] = cnn[nb + (long long)ch2 * 16384 + off];
                gv[j][3] = cnn[nb + (long long)ch3 * 16384 + off];
            }
        }
    }
    conv1_half(s0, s1, wB, b1, 0, oy - 6, ox - 6, wave, lane);
#pragma unroll
    for (int j = 0; j < 4; ++j) {
        int idx = tid + 256 * j;
        if (idx < 792) {
            uint2 v; v.x = pack2(gv[j][0], gv[j][1]); v.y = pack2(gv[j][2], gv[j][3]);
            *(uint2*)(sin_ + idx * 4) = v;
        }
    }
    __syncthreads();

    conv0_slab(sin_, s0, wB, b0, 14, oy, ox, wave, lane);      // s0 rows 14..31
    __syncthreads();

    conv1_half(s0, s1, wB, b1, 392, oy - 6, ox - 6, wave, lane);
    __syncthreads();

    conv2_fp8(s1, s2, wB, b2, oy - 4, ox - 4, wave, lane);
    __syncthreads();

    conv_c32_fp8<24, 20, 7, true,  true >(s2, s3, wB + 38912, b3, oy - 2, ox - 2, wave, lane);
    __syncthreads();

    conv_c32_fp8<20, 16, 4, false, false>(s3, s4, wB + 64512, b4, oy, ox, wave, lane);
    __syncthreads();

    // ---- conv5 (1x1 32->128) bf16 + relu + conv6 (128->2)
    {
        const unsigned short* w5p = (const unsigned short*)(wB + 13312);
        bf16x8 w5f[8];
#pragma unroll
        for (int nt = 0; nt < 8; ++nt)
            w5f[nt] = *(const bf16x8*)(w5p + nt * 512 + nl * 32 + quad * 8);
        const float b6q = b6[quad & 1];
#pragma unroll 1
        for (int ii = 0; ii < 4; ++ii) {
            int mt = wave + 4 * ii;                // 16 mtiles
            int lin = (mt * 16 + nl) * 64 + quad * 16;
            bf16x8 pf = *(const bf16x8*)(s4 + sw48(lin));
            float o0 = 0.f, o1 = 0.f;
#pragma unroll
            for (int nt = 0; nt < 8; ++nt) {
                f32x4 acc = (f32x4)0.f;
                acc = __builtin_amdgcn_mfma_f32_16x16x32_bf16(w5f[nt], pf, acc, 0, 0, 0);
                float4 bb  = *(const float4*)(b5 + nt * 16 + quad * 4);
                float4 wa  = *(const float4*)(w6 + nt * 16 + quad * 4);
                float4 wb2 = *(const float4*)(w6 + 128 + nt * 16 + quad * 4);
                float h0 = fmaxf(acc[0] + bb.x, 0.f), h1 = fmaxf(acc[1] + bb.y, 0.f);
                float h2 = fmaxf(acc[2] + bb.z, 0.f), h3 = fmaxf(acc[3] + bb.w, 0.f);
                o0 = fmaf(h0, wa.x, fmaf(h1, wa.y, fmaf(h2, wa.z, fmaf(h3, wa.w, o0))));
                o1 = fmaf(h0, wb2.x, fmaf(h1, wb2.y, fmaf(h2, wb2.z, fmaf(h3, wb2.w, o1))));
            }
            o0 += __shfl_xor(o0, 16, 64); o0 += __shfl_xor(o0, 32, 64);
            o1 += __shfl_xor(o1, 16, 64); o1 += __shfl_xor(o1, 32, 64);
            if (quad < 2) {
                float val = ((quad == 0) ? o0 : o1) + b6q;
                long long ob = (((long long)n * 38 + 2 * g + quad) * 128 + (oy + mt)) * 128 + (ox + nl);
                out[ob] = val;
            }
        }
    }
}

extern "C" void kernel_launch(void* const* d_in, const int* in_sizes, int n_in,
                              void* d_out, int out_size, void* d_ws, size_t ws_size,
                              hipStream_t stream) {
    const float* cnn = (const float*)d_in[0];
    const float* w0 = (const float*)d_in[2];  const float* b0 = (const float*)d_in[3];
    const float* w1 = (const float*)d_in[4];  const float* b1 = (const float*)d_in[5];
    const float* w2 = (const float*)d_in[6];  const float* b2 = (const float*)d_in[7];
    const float* w3 = (const float*)d_in[8];  const float* b3 = (const float*)d_in[9];
    const float* w4 = (const float*)d_in[10]; const float* b4 = (const float*)d_in[11];
    const float* w5 = (const float*)d_in[12]; const float* b5 = (const float*)d_in[13];
    const float* w6 = (const float*)d_in[14]; const float* b6 = (const float*)d_in[15];
    float* out = (float*)d_out;
    unsigned char* wB = (unsigned char*)d_ws;   // 90112 B used

    hipLaunchKernelGGL(reorder_weights, dim3(252), dim3(256), 0, stream,
                       w0, w1, w2, w3, w4, w5, wB);
    hipLaunchKernelGGL(gnn_paf_mfma, dim3(64, 304), dim3(256), 0, stream,
                       cnn, wB, b0, b1, b2, b3, b4, b5, w6, b6, out);
}

// Round 12
// 1295.921 us; speedup vs baseline: 1.6657x; 1.2617x over previous
//
#include <hip/hip_runtime.h>
#include <hip/hip_bf16.h>

typedef __bf16  bf16x8 __attribute__((ext_vector_type(8)));
typedef float   f32x4  __attribute__((ext_vector_type(4)));

__device__ __constant__ int EDGE_A[19] = {1,8,9,1,11,12,1,2,3,2,1,5,6,5,0,0,0,14,15};
__device__ __constant__ int EDGE_B[19] = {8,9,10,11,12,13,2,3,4,16,5,6,7,17,1,14,15,16,17};

#define SINV (1.0f / 4096.0f)   // 1/(Sw*Sa), Sw=Sa=64
#define SACT 64.0f

__device__ __forceinline__ unsigned short f2bf(float f) {
    unsigned int x = __float_as_uint(f);
    x += 0x7FFFu + ((x >> 16) & 1u);
    return (unsigned short)(x >> 16);
}
__device__ __forceinline__ unsigned int pack2(float a, float b) {
    __hip_bfloat162 t = __float22bfloat162_rn(make_float2(a, b));
    unsigned int r; __builtin_memcpy(&r, &t, 4); return r;
}
__device__ __forceinline__ unsigned char f2fp8(float v) {
    int r = __builtin_amdgcn_cvt_pk_fp8_f32(v, 0.f, 0, false);
    return (unsigned char)(r & 0xff);
}
__device__ __forceinline__ unsigned int pk4fp8(float a, float b, float c, float d) {
    int v = __builtin_amdgcn_cvt_pk_fp8_f32(a, b, 0, false);
    v = __builtin_amdgcn_cvt_pk_fp8_f32(c, d, v, true);
    return (unsigned int)v;
}

// swizzles (granule-preserving XOR)
__device__ __forceinline__ int sw16(int l) { return l ^ ((l >> 3) & 16); }  // 32B rows, 16B units
__device__ __forceinline__ int sw8 (int l) { return l ^ ((l >> 4) & 8);  }  // 16B rows, 8B units
__device__ __forceinline__ int sw32(int l) { return l ^ ((l >> 5) & 24); }  // 32B rows, 8B units
__device__ __forceinline__ int sw48(int l) { return l ^ ((l >> 3) & 48); }  // 64B rows, 16B units

__device__ __forceinline__ void store_relu4(unsigned char* dst, f32x4 a, float4 b, bool oob) {
    unsigned int lo = pack2(fmaxf(a[0] + b.x, 0.f), fmaxf(a[1] + b.y, 0.f));
    unsigned int hi = pack2(fmaxf(a[2] + b.z, 0.f), fmaxf(a[3] + b.w, 0.f));
    uint2 v; v.x = oob ? 0u : lo; v.y = oob ? 0u : hi;
    *(uint2*)dst = v;
}

// ---------------------------------------------------------------------------
// Weight pre-pass, ws BYTE layout:
//   W1 bf16 @0     : 13tp x 16n x 32k shorts              (13312 B)
//   W5 bf16 @13312 : 8nt x 16 x 32 shorts                 ( 8192 B)
//   W0 bf16 @21504 : 4c x 16 x 32 shorts                  ( 4096 B)
//   W2 fp8  @25600 : 13tp x 2nt x 16n x 32k bytes, x64    (13312 B)
//   W3 fp8  @38912 : 25tap x 2nt x 16 x 32 (k=ic), x64    (25600 B)
//   W4 fp8  @64512 : 25tap x 2nt x 16 x 32 (k=ic), x64    (25600 B)
// ---------------------------------------------------------------------------
extern "C" __global__ void __launch_bounds__(256)
reorder_weights(const float* __restrict__ w0, const float* __restrict__ w1,
                const float* __restrict__ w2, const float* __restrict__ w3,
                const float* __restrict__ w4, const float* __restrict__ w5,
                unsigned char* __restrict__ ws)
{
    int idx = blockIdx.x * 256 + threadIdx.x;
    unsigned short* wsS = (unsigned short*)ws;
    if (idx < 6656) {                       // W1 (shorts 0..6655)
        int k = idx & 31, n = (idx >> 5) & 15, tp = idx >> 9;
        int t = 2 * tp + (k >> 4), ic = k & 15;
        float v = (t < 25) ? w1[(n * 16 + ic) * 25 + t] : 0.f;
        wsS[idx] = f2bf(v);
    } else if (idx < 10752) {               // W5
        int j = idx - 6656;
        int k = j & 31, oc = j >> 5;
        wsS[idx] = f2bf(w5[oc * 32 + k]);
    } else if (idx < 12800) {               // W0
        int j = idx - 10752;
        int k = j & 31, n = (j >> 5) & 15, c = j >> 9;
        int t = c * 8 + (k >> 2), ic = k & 3;
        float v = (t < 25) ? w0[(n * 4 + ic) * 25 + t] : 0.f;
        wsS[idx] = f2bf(v);
    }
    if (idx < 13312) {                      // W2 fp8
        int k = idx & 31, n = (idx >> 5) & 15, nt = (idx >> 9) & 1, tp = idx >> 10;
        int t = 2 * tp + (k >> 4), ic = k & 15, oc = nt * 16 + n;
        float v = (t < 25) ? w2[(oc * 16 + ic) * 25 + t] * SACT : 0.f;
        ws[25600 + idx] = f2fp8(v);
    } else if (idx < 38912) {               // W3 fp8
        int j = idx - 13312;
        int k = j & 31, n = (j >> 5) & 15, nt = (j >> 9) & 1, tap = j >> 10;
        ws[25600 + idx] = f2fp8(w3[((nt * 16 + n) * 32 + k) * 25 + tap] * SACT);
    } else if (idx < 64512) {               // W4 fp8
        int j = idx - 38912;
        int k = j & 31, n = (j >> 5) & 15, nt = (j >> 9) & 1, tap = j >> 10;
        ws[25600 + idx] = f2fp8(w4[((nt * 16 + n) * 32 + k) * 25 + tap] * SACT);
    }
}

// ---------------------------------------------------------------------------
// conv0 (4->16) bf16 on an 18-row slab: 36 mtiles; out s0 [px][32B] sw16.
// ---------------------------------------------------------------------------
__device__ __forceinline__ void conv0_slab(
    const unsigned short* __restrict__ s_in, unsigned char* __restrict__ s0,
    const unsigned char* __restrict__ wB, const float* __restrict__ b0,
    int yoff, int oy, int ox, int wave, int lane)
{
    const int nl = lane & 15, quad = lane >> 4;
    const unsigned short* w0p = (const unsigned short*)(wB + 21504);
    bf16x8 wf[4];
#pragma unroll
    for (int c = 0; c < 4; ++c)
        wf[c] = *(const bf16x8*)(w0p + c * 512 + nl * 32 + quad * 8);
    float4 bb = *(const float4*)(b0 + quad * 4);
#pragma unroll 1
    for (int i = 0; i < 9; ++i) {
        int mt = wave + 4 * i;
        int p = mt * 16 + nl;
        int y = p >> 5, x = p & 31;
        f32x4 acc = (f32x4)0.f;
#pragma unroll
        for (int c = 0; c < 4; ++c) {
            int t0 = c * 8 + quad * 2, t1 = t0 + 1;
            if (t0 > 24) t0 = 24;
            if (t1 > 24) t1 = 24;
            int dy0 = t0 / 5, dx0 = t0 - 5 * dy0;
            int dy1 = t1 / 5, dx1 = t1 - 5 * dy1;
            uint2 lo = *(const uint2*)(s_in + ((y + dy0) * 36 + x + dx0) * 4);
            uint2 hi = *(const uint2*)(s_in + ((y + dy1) * 36 + x + dx1) * 4);
            bf16x8 a;
            ((uint2*)&a)[0] = lo; ((uint2*)&a)[1] = hi;
            acc = __builtin_amdgcn_mfma_f32_16x16x32_bf16(wf[c], a, acc, 0, 0, 0);
        }
        bool oob = ((unsigned)(oy - 8 + y + yoff) >= 128u) || ((unsigned)(ox - 8 + x) >= 128u);
        store_relu4(s0 + sw16(p * 32 + quad * 8), acc, bb, oob);
    }
}

// ---------------------------------------------------------------------------
// conv1 half-slab: bf16 in (s0, 18 rows x 32 wide), fp8 x64 out (s1 16B rows).
// ---------------------------------------------------------------------------
__device__ __forceinline__ void conv1_half(
    const unsigned char* __restrict__ s0, unsigned char* __restrict__ s1,
    const unsigned char* __restrict__ wB, const float* __restrict__ b1,
    int POFF, int gy0, int gx0, int wave, int lane)
{
    const int nl = lane & 15, quad = lane >> 4;
    const int h = quad >> 1, coff = (quad & 1) * 16;

    int abase[7];
#pragma unroll
    for (int i = 0; i < 7; ++i) {
        int p = (wave + 4 * i) * 16 + nl;
        if (p > 391) p = 391;
        int y = p / 28, x = p - y * 28;
        abase[i] = (y * 32 + x) * 32 + coff;
    }
    f32x4 acc[7];
#pragma unroll
    for (int i = 0; i < 7; ++i) acc[i] = (f32x4)0.f;

    const unsigned short* wp = (const unsigned short*)(wB) + nl * 32 + quad * 8;

#pragma unroll 1
    for (int c0 = 0; c0 < 13; c0 += 5) {
        bf16x8 wf[5];
#pragma unroll
        for (int tp = 0; tp < 5; ++tp)
            if (c0 + tp < 13) wf[tp] = *(const bf16x8*)(wp + (c0 + tp) * 512);
#pragma unroll
        for (int tp = 0; tp < 5; ++tp) {
            if (c0 + tp < 13) {
                int t = 2 * (c0 + tp) + h;
                if (t > 24) t = 24;
                int dy = t / 5, dx = t - 5 * dy;
                int toff = (dy * 32 + dx) * 32;
#pragma unroll
                for (int i = 0; i < 7; ++i)
                    if (wave + 4 * i < 25) {
                        bf16x8 a = *(const bf16x8*)(s0 + sw16(abase[i] + toff));
                        acc[i] = __builtin_amdgcn_mfma_f32_16x16x32_bf16(wf[tp], a, acc[i], 0, 0, 0);
                    }
            }
        }
    }

    float4 bb = *(const float4*)(b1 + quad * 4);
#pragma unroll
    for (int i = 0; i < 7; ++i) {
        int p = (wave + 4 * i) * 16 + nl;
        if (p < 392) {
            int pg = p + POFF;
            int y = pg / 28, x = pg - y * 28;
            bool oob = ((unsigned)(gy0 + y) >= 128u) || ((unsigned)(gx0 + x) >= 128u);
            unsigned int v = pk4fp8(fmaxf(acc[i][0] + bb.x, 0.f) * SACT,
                                    fmaxf(acc[i][1] + bb.y, 0.f) * SACT,
                                    fmaxf(acc[i][2] + bb.z, 0.f) * SACT,
                                    fmaxf(acc[i][3] + bb.w, 0.f) * SACT);
            *(unsigned int*)(s1 + sw8(pg * 16 + quad * 4)) = oob ? 0u : v;
        }
    }
}

// ---------------------------------------------------------------------------
// conv2: fp8 paired-tap (CIN=16, K=32=2tp x 16ch), NT=2. Split into two
// m-passes (I0/NI) to keep live accumulators <=40 VGPRs -> no spills under
// the 128-reg/4-block budget.
// ---------------------------------------------------------------------------
template<int I0, int NI>
__device__ __forceinline__ void conv2_fp8(
    const unsigned char* __restrict__ s1, unsigned char* __restrict__ s2,
    const unsigned char* __restrict__ wB, const float* __restrict__ b2,
    int gy0, int gx0, int wave, int lane)
{
    const int nl = lane & 15, quad = lane >> 4;
    const int h = quad >> 1, g8 = (quad & 1) * 8;

    int abase[NI];
#pragma unroll
    for (int i = 0; i < NI; ++i) {
        int p = (wave + 4 * (I0 + i)) * 16 + nl;
        int y = p / 24, x = p - y * 24;
        abase[i] = (y * 28 + x) * 16 + g8;
    }
    f32x4 acc[NI][2];
#pragma unroll
    for (int i = 0; i < NI; ++i) { acc[i][0] = (f32x4)0.f; acc[i][1] = (f32x4)0.f; }

    const unsigned char* wp = wB + 25600 + nl * 32 + quad * 8;

#pragma unroll 1
    for (int c0 = 0; c0 < 13; c0 += 3) {
        long wl[3][2];
#pragma unroll
        for (int tp = 0; tp < 3; ++tp)
            if (c0 + tp < 13) {
                wl[tp][0] = *(const long*)(wp + ((c0 + tp) * 2 + 0) * 512);
                wl[tp][1] = *(const long*)(wp + ((c0 + tp) * 2 + 1) * 512);
            }
#pragma unroll
        for (int tp = 0; tp < 3; ++tp) {
            if (c0 + tp < 13) {
                int t = 2 * (c0 + tp) + h;
                if (t > 24) t = 24;
                int dy = t / 5, dx = t - 5 * dy;
                int toff = (dy * 28 + dx) * 16;
#pragma unroll
                for (int i = 0; i < NI; ++i) {
                    long a = *(const long*)(s1 + sw8(abase[i] + toff));
                    acc[i][0] = __builtin_amdgcn_mfma_f32_16x16x32_fp8_fp8(wl[tp][0], a, acc[i][0], 0, 0, 0);
                    acc[i][1] = __builtin_amdgcn_mfma_f32_16x16x32_fp8_fp8(wl[tp][1], a, acc[i][1], 0, 0, 0);
                }
            }
        }
    }

#pragma unroll
    for (int i = 0; i < NI; ++i) {
        int p = (wave + 4 * (I0 + i)) * 16 + nl;
        int y = p / 24, x = p - y * 24;
        bool oob = ((unsigned)(gy0 + y) >= 128u) || ((unsigned)(gx0 + x) >= 128u);
#pragma unroll
        for (int nt = 0; nt < 2; ++nt) {
            float4 bb = *(const float4*)(b2 + nt * 16 + quad * 4);
            unsigned int v = pk4fp8(fmaxf(acc[i][nt][0] * SINV + bb.x, 0.f) * SACT,
                                    fmaxf(acc[i][nt][1] * SINV + bb.y, 0.f) * SACT,
                                    fmaxf(acc[i][nt][2] * SINV + bb.z, 0.f) * SACT,
                                    fmaxf(acc[i][nt][3] * SINV + bb.w, 0.f) * SACT);
            *(unsigned int*)(s2 + sw32(p * 32 + nt * 16 + quad * 4)) = oob ? 0u : v;
        }
    }
}

// ---------------------------------------------------------------------------
// conv3/conv4: fp8 25-tap (CIN=32, K=32=ic), NT=2, chunk CH taps.
// FP8OUT: fp8 x64 to 32B rows (sw32); else bf16 to 64B rows (sw48).
// ---------------------------------------------------------------------------
template<int SIN, int SOUT, int MAXM, bool GUARD, bool FP8OUT, int CH>
__device__ __forceinline__ void conv_c32_fp8(
    const unsigned char* __restrict__ sinB, unsigned char* __restrict__ soutB,
    const unsigned char* __restrict__ wA, const float* __restrict__ bias,
    int gy0, int gx0, int wave, int lane)
{
    constexpr int NM = (SOUT * SOUT) / 16;
    const int nl = lane & 15, quad = lane >> 4;

    int abase[MAXM];
#pragma unroll
    for (int i = 0; i < MAXM; ++i) {
        int p = (wave + 4 * i) * 16 + nl;
        if (GUARD && p > SOUT * SOUT - 1) p = SOUT * SOUT - 1;
        int y = p / SOUT, x = p - y * SOUT;
        abase[i] = (y * SIN + x) * 32 + quad * 8;
    }
    f32x4 acc[MAXM][2];
#pragma unroll
    for (int i = 0; i < MAXM; ++i) { acc[i][0] = (f32x4)0.f; acc[i][1] = (f32x4)0.f; }

    const unsigned char* wp = wA + nl * 32 + quad * 8;

#pragma unroll 1
    for (int c0 = 0; c0 < 25; c0 += CH) {
        long wl[CH][2];
#pragma unroll
        for (int tp = 0; tp < CH; ++tp)
            if (c0 + tp < 25) {
                wl[tp][0] = *(const long*)(wp + ((c0 + tp) * 2 + 0) * 512);
                wl[tp][1] = *(const long*)(wp + ((c0 + tp) * 2 + 1) * 512);
            }
#pragma unroll
        for (int tp = 0; tp < CH; ++tp) {
            if (c0 + tp < 25) {
                int t = c0 + tp;
                int dy = t / 5, dx = t - 5 * dy;
                int toff = (dy * SIN + dx) * 32;
#pragma unroll
                for (int i = 0; i < MAXM; ++i)
                    if (!GUARD || wave + 4 * i < NM) {
                        long a = *(const long*)(sinB + sw32(abase[i] + toff));
                        acc[i][0] = __builtin_amdgcn_mfma_f32_16x16x32_fp8_fp8(wl[tp][0], a, acc[i][0], 0, 0, 0);
                        acc[i][1] = __builtin_amdgcn_mfma_f32_16x16x32_fp8_fp8(wl[tp][1], a, acc[i][1], 0, 0, 0);
                    }
            }
        }
    }

#pragma unroll
    for (int i = 0; i < MAXM; ++i) {
        int p = (wave + 4 * i) * 16 + nl;
        if (!GUARD || p < SOUT * SOUT) {
            int y = p / SOUT, x = p - y * SOUT;
            bool oob = ((unsigned)(gy0 + y) >= 128u) || ((unsigned)(gx0 + x) >= 128u);
#pragma unroll
            for (int nt = 0; nt < 2; ++nt) {
                float4 bb = *(const float4*)(bias + nt * 16 + quad * 4);
                if (FP8OUT) {
                    unsigned int v = pk4fp8(fmaxf(acc[i][nt][0] * SINV + bb.x, 0.f) * SACT,
                                            fmaxf(acc[i][nt][1] * SINV + bb.y, 0.f) * SACT,
                                            fmaxf(acc[i][nt][2] * SINV + bb.z, 0.f) * SACT,
                                            fmaxf(acc[i][nt][3] * SINV + bb.w, 0.f) * SACT);
                    *(unsigned int*)(soutB + sw32(p * 32 + nt * 16 + quad * 4)) = oob ? 0u : v;
                } else {
                    f32x4 s;
                    s[0] = acc[i][nt][0] * SINV; s[1] = acc[i][nt][1] * SINV;
                    s[2] = acc[i][nt][2] * SINV; s[3] = acc[i][nt][3] * SINV;
                    store_relu4(soutB + sw48(p * 64 + nt * 32 + quad * 8), s, bb, oob);
                }
            }
        }
    }
}

// ---------------------------------------------------------------------------
// Fused pipeline: 256 threads = one 16x16 output tile. launch_bounds(256,3)
// is a register CEILING (170); target allocation <=128 -> 4 blocks/CU.
// LDS 37568 B: S1@0 12544 | S3@0 12800 | SIN@12800 6336 | S0/S2/S4@19136
// ---------------------------------------------------------------------------
extern "C" __global__ void __launch_bounds__(256, 3)
gnn_paf_mfma(const float* __restrict__ cnn, const unsigned char* __restrict__ wB,
             const float* __restrict__ b0, const float* __restrict__ b1,
             const float* __restrict__ b2, const float* __restrict__ b3,
             const float* __restrict__ b4, const float* __restrict__ b5,
             const float* __restrict__ w6, const float* __restrict__ b6,
             float* __restrict__ out)
{
    __shared__ __align__(64) unsigned char smem[37568];
    unsigned char*  const s1   = smem;                             // 12544
    unsigned char*  const s3   = smem;                             // 12800
    unsigned short* const sin_ = (unsigned short*)(smem + 12800);  // 6336
    unsigned char*  const s0   = smem + 19136;                     // 18432
    unsigned char*  const s2   = smem + 19136;                     // 18432
    unsigned char*  const s4   = smem + 19136;                     // 16384

    const int tid  = threadIdx.x;
    const int lane = tid & 63, wave = tid >> 6;       // 4 waves
    const int tile = blockIdx.x, img = blockIdx.y;
    const int oy = (tile >> 3) * 16, ox = (tile & 7) * 16;
    const int n = img / 19, g = img - n * 19;
    const int ch0 = EDGE_A[g], ch1 = EDGE_B[g], ch2 = 19 + 2 * g, ch3 = 20 + 2 * g;
    const int nl = lane & 15, quad = lane >> 4;
    const long long nb = (long long)n * 57 * 16384;

    // ---- gatherA: halo rows 0..21 -> sin_ (22x36x4 bf16, zero-padded)
    for (int idx = tid; idx < 792; idx += 256) {
        int r = idx / 36, c = idx - r * 36;
        int gy = oy - 10 + r, gx = ox - 10 + c;
        float v0 = 0.f, v1 = 0.f, v2 = 0.f, v3 = 0.f;
        if ((unsigned)gy < 128u && (unsigned)gx < 128u) {
            int off = gy * 128 + gx;
            v0 = cnn[nb + (long long)ch0 * 16384 + off];
            v1 = cnn[nb + (long long)ch1 * 16384 + off];
            v2 = cnn[nb + (long long)ch2 * 16384 + off];
            v3 = cnn[nb + (long long)ch3 * 16384 + off];
        }
        uint2 v; v.x = pack2(v0, v1); v.y = pack2(v2, v3);
        *(uint2*)(sin_ + idx * 4) = v;
    }
    __syncthreads();

    conv0_slab(sin_, s0, wB, b0, 0, oy, ox, wave, lane);       // s0 rows 0..17
    __syncthreads();

    // gatherB loads (input rows 14..35) pipelined across conv1a
    float gv[4][4];
#pragma unroll
    for (int j = 0; j < 4; ++j) {
        gv[j][0] = gv[j][1] = gv[j][2] = gv[j][3] = 0.f;
        int idx = tid + 256 * j;
        if (idx < 792) {
            int r = idx / 36, c = idx - r * 36;
            int gy = oy + 4 + r, gx = ox - 10 + c;
            if ((unsigned)gy < 128u && (unsigned)gx < 128u) {
                int off = gy * 128 + gx;
                gv[j][0] = cnn[nb + (long long)ch0 * 16384 + off];
                gv[j][1] = cnn[nb + (long long)ch1 * 16384 + off];
                gv[j][2] = cnn[nb + (long long)ch2 * 16384 + off];
                gv[j][3] = cnn[nb + (long long)ch3 * 16384 + off];
            }
        }
    }
    conv1_half(s0, s1, wB, b1, 0, oy - 6, ox - 6, wave, lane);
#pragma unroll
    for (int j = 0; j < 4; ++j) {
        int idx = tid + 256 * j;
        if (idx < 792) {
            uint2 v; v.x = pack2(gv[j][0], gv[j][1]); v.y = pack2(gv[j][2], gv[j][3]);
            *(uint2*)(sin_ + idx * 4) = v;
        }
    }
    __syncthreads();

    conv0_slab(sin_, s0, wB, b0, 14, oy, ox, wave, lane);      // s0 rows 14..31
    __syncthreads();

    conv1_half(s0, s1, wB, b1, 392, oy - 6, ox - 6, wave, lane);
    __syncthreads();

    conv2_fp8<0, 5>(s1, s2, wB, b2, oy - 4, ox - 4, wave, lane);
    conv2_fp8<5, 4>(s1, s2, wB, b2, oy - 4, ox - 4, wave, lane);
    __syncthreads();

    conv_c32_fp8<24, 20, 7, true,  true,  3>(s2, s3, wB + 38912, b3, oy - 2, ox - 2, wave, lane);
    __syncthreads();

    conv_c32_fp8<20, 16, 4, false, false, 5>(s3, s4, wB + 64512, b4, oy, ox, wave, lane);
    __syncthreads();

    // ---- conv5 (1x1 32->128) bf16 + relu + conv6 (128->2)
    {
        const unsigned short* w5p = (const unsigned short*)(wB + 13312);
        bf16x8 w5f[8];
#pragma unroll
        for (int nt = 0; nt < 8; ++nt)
            w5f[nt] = *(const bf16x8*)(w5p + nt * 512 + nl * 32 + quad * 8);
        const float b6q = b6[quad & 1];
#pragma unroll 1
        for (int ii = 0; ii < 4; ++ii) {
            int mt = wave + 4 * ii;                // 16 mtiles
            int lin = (mt * 16 + nl) * 64 + quad * 16;
            bf16x8 pf = *(const bf16x8*)(s4 + sw48(lin));
            float o0 = 0.f, o1 = 0.f;
#pragma unroll
            for (int nt = 0; nt < 8; ++nt) {
                f32x4 acc = (f32x4)0.f;
                acc = __builtin_amdgcn_mfma_f32_16x16x32_bf16(w5f[nt], pf, acc, 0, 0, 0);
                float4 bb  = *(const float4*)(b5 + nt * 16 + quad * 4);
                float4 wa  = *(const float4*)(w6 + nt * 16 + quad * 4);
                float4 wb2 = *(const float4*)(w6 + 128 + nt * 16 + quad * 4);
                float h0 = fmaxf(acc[0] + bb.x, 0.f), h1 = fmaxf(acc[1] + bb.y, 0.f);
                float h2 = fmaxf(acc[2] + bb.z, 0.f), h3 = fmaxf(acc[3] + bb.w, 0.f);
                o0 = fmaf(h0, wa.x, fmaf(h1, wa.y, fmaf(h2, wa.z, fmaf(h3, wa.w, o0))));
                o1 = fmaf(h0, wb2.x, fmaf(h1, wb2.y, fmaf(h2, wb2.z, fmaf(h3, wb2.w, o1))));
            }
            o0 += __shfl_xor(o0, 16, 64); o0 += __shfl_xor(o0, 32, 64);
            o1 += __shfl_xor(o1, 16, 64); o1 += __shfl_xor(o1, 32, 64);
            if (quad < 2) {
                float val = ((quad == 0) ? o0 : o1) + b6q;
                long long ob = (((long long)n * 38 + 2 * g + quad) * 128 + (oy + mt)) * 128 + (ox + nl);
                out[ob] = val;
            }
        }
    }
}

extern "C" void kernel_launch(void* const* d_in, const int* in_sizes, int n_in,
                              void* d_out, int out_size, void* d_ws, size_t ws_size,
                              hipStream_t stream) {
    const float* cnn = (const float*)d_in[0];
    const float* w0 = (const float*)d_in[2];  const float* b0 = (const float*)d_in[3];
    const float* w1 = (const float*)d_in[4];  const float* b1 = (const float*)d_in[5];
    const float* w2 = (const float*)d_in[6];  const float* b2 = (const float*)d_in[7];
    const float* w3 = (const float*)d_in[8];  const float* b3 = (const float*)d_in[9];
    const float* w4 = (const float*)d_in[10]; const float* b4 = (const float*)d_in[11];
    const float* w5 = (const float*)d_in[12]; const float* b5 = (const float*)d_in[13];
    const float* w6 = (const float*)d_in[14]; const float* b6 = (const float*)d_in[15];
    float* out = (float*)d_out;
    unsigned char* wB = (unsigned char*)d_ws;   // 90112 B used

    hipLaunchKernelGGL(reorder_weights, dim3(252), dim3(256), 0, stream,
                       w0, w1, w2, w3, w4, w5, wB);
    hipLaunchKernelGGL(gnn_paf_mfma, dim3(64, 304), dim3(256), 0, stream,
                       cnn, wB, b0, b1, b2, b3, b4, b5, w6, b6, out);
}

// Round 13
// 1250.225 us; speedup vs baseline: 1.7266x; 1.0366x over previous
//
#include <hip/hip_runtime.h>
#include <hip/hip_bf16.h>

typedef __bf16  bf16x8 __attribute__((ext_vector_type(8)));
typedef float   f32x4  __attribute__((ext_vector_type(4)));

__device__ __constant__ int EDGE_A[19] = {1,8,9,1,11,12,1,2,3,2,1,5,6,5,0,0,0,14,15};
__device__ __constant__ int EDGE_B[19] = {8,9,10,11,12,13,2,3,4,16,5,6,7,17,1,14,15,16,17};

#define SACT  64.0f            // activation & weight quant scale
#define SINV  (1.0f / 4096.0f) // 1/(Sw*Sa)
#define SREQ  0.015625f        // SINV*SACT = 1/64 (requant multiplier)

__device__ __forceinline__ unsigned short f2bf(float f) {
    unsigned int x = __float_as_uint(f);
    x += 0x7FFFu + ((x >> 16) & 1u);
    return (unsigned short)(x >> 16);
}
__device__ __forceinline__ unsigned int pack2(float a, float b) {
    __hip_bfloat162 t = __float22bfloat162_rn(make_float2(a, b));
    unsigned int r; __builtin_memcpy(&r, &t, 4); return r;
}
__device__ __forceinline__ unsigned char f2fp8(float v) {
    int r = __builtin_amdgcn_cvt_pk_fp8_f32(v, 0.f, 0, false);
    return (unsigned char)(r & 0xff);
}
__device__ __forceinline__ unsigned int pk4fp8(float a, float b, float c, float d) {
    int v = __builtin_amdgcn_cvt_pk_fp8_f32(a, b, 0, false);
    v = __builtin_amdgcn_cvt_pk_fp8_f32(c, d, v, true);
    return (unsigned int)v;
}
// quantized epilogue: relu(acc*s + bias_prescaled) -> fp8x4
__device__ __forceinline__ unsigned int quant4(f32x4 a, float4 b, float s, bool oob) {
    float v0 = fmaxf(fmaf(a[0], s, b.x), 0.f);
    float v1 = fmaxf(fmaf(a[1], s, b.y), 0.f);
    float v2 = fmaxf(fmaf(a[2], s, b.z), 0.f);
    float v3 = fmaxf(fmaf(a[3], s, b.w), 0.f);
    unsigned int v = pk4fp8(v0, v1, v2, v3);
    return oob ? 0u : v;
}

// swizzles (granule-preserving XOR)
__device__ __forceinline__ int sw8 (int l) { return l ^ ((l >> 4) & 8);  }  // 16B rows
__device__ __forceinline__ int sw32(int l) { return l ^ ((l >> 5) & 24); }  // 32B rows
__device__ __forceinline__ int sw48(int l) { return l ^ ((l >> 3) & 48); }  // 64B rows

__device__ __forceinline__ void store_relu4(unsigned char* dst, f32x4 a, float4 b, bool oob) {
    unsigned int lo = pack2(fmaxf(a[0] + b.x, 0.f), fmaxf(a[1] + b.y, 0.f));
    unsigned int hi = pack2(fmaxf(a[2] + b.z, 0.f), fmaxf(a[3] + b.w, 0.f));
    uint2 v; v.x = oob ? 0u : lo; v.y = oob ? 0u : hi;
    *(uint2*)dst = v;
}

// ---------------------------------------------------------------------------
// Weight pre-pass, ws BYTE layout:
//   W5 bf16 @0     : 8nt x 16 x 32 shorts            ( 8192 B)
//   W0 bf16 @8192  : 4c x 16 x 32 shorts             ( 4096 B)
//   W1 fp8  @12288 : 13tp x 16n x 32k, x64           ( 6656 B)
//   W2 fp8  @18944 : 13tp x 2nt x 16 x 32, x64       (13312 B)
//   W3 fp8  @32256 : 25tap x 2nt x 16 x 32 (k=ic)    (25600 B)
//   W4 fp8  @57856 : 25tap x 2nt x 16 x 32 (k=ic)    (25600 B)
// total 83456 B
// ---------------------------------------------------------------------------
extern "C" __global__ void __launch_bounds__(256)
reorder_weights(const float* __restrict__ w0, const float* __restrict__ w1,
                const float* __restrict__ w2, const float* __restrict__ w3,
                const float* __restrict__ w4, const float* __restrict__ w5,
                unsigned char* __restrict__ ws)
{
    int idx = blockIdx.x * 256 + threadIdx.x;
    unsigned short* wsS = (unsigned short*)ws;
    if (idx < 4096) {                       // W5 bf16
        int k = idx & 31, oc = idx >> 5;
        wsS[idx] = f2bf(w5[oc * 32 + k]);
    } else if (idx < 6144) {                // W0 bf16
        int j = idx - 4096;
        int k = j & 31, n = (j >> 5) & 15, c = j >> 9;
        int t = c * 8 + (k >> 2), ic = k & 3;
        float v = (t < 25) ? w0[(n * 4 + ic) * 25 + t] : 0.f;
        wsS[idx] = f2bf(v);
    }
    if (idx < 6656) {                       // W1 fp8
        int k = idx & 31, n = (idx >> 5) & 15, tp = idx >> 9;
        int t = 2 * tp + (k >> 4), ic = k & 15;
        float v = (t < 25) ? w1[(n * 16 + ic) * 25 + t] * SACT : 0.f;
        ws[12288 + idx] = f2fp8(v);
    } else if (idx < 19968) {               // W2 fp8
        int j = idx - 6656;
        int k = j & 31, n = (j >> 5) & 15, nt = (j >> 9) & 1, tp = j >> 10;
        int t = 2 * tp + (k >> 4), ic = k & 15, oc = nt * 16 + n;
        float v = (t < 25) ? w2[(oc * 16 + ic) * 25 + t] * SACT : 0.f;
        ws[18944 + j] = f2fp8(v);
    } else if (idx < 45568) {               // W3 fp8
        int j = idx - 19968;
        int k = j & 31, n = (j >> 5) & 15, nt = (j >> 9) & 1, tap = j >> 10;
        ws[32256 + j] = f2fp8(w3[((nt * 16 + n) * 32 + k) * 25 + tap] * SACT);
    } else if (idx < 71168) {               // W4 fp8
        int j = idx - 45568;
        int k = j & 31, n = (j >> 5) & 15, nt = (j >> 9) & 1, tap = j >> 10;
        ws[57856 + j] = f2fp8(w4[((nt * 16 + n) * 32 + k) * 25 + tap] * SACT);
    }
}

// ---------------------------------------------------------------------------
// conv0 (4->16) bf16 MFMA on an 18-row slab; OUTPUT fp8 x64 -> s0 16B rows.
// ---------------------------------------------------------------------------
__device__ __forceinline__ void conv0_slab(
    const unsigned short* __restrict__ s_in, unsigned char* __restrict__ s0,
    const unsigned char* __restrict__ wB, const float* __restrict__ b0,
    int yoff, int oy, int ox, int wave, int lane)
{
    const int nl = lane & 15, quad = lane >> 4;
    const unsigned short* w0p = (const unsigned short*)(wB + 8192);
    bf16x8 wf[4];
#pragma unroll
    for (int c = 0; c < 4; ++c)
        wf[c] = *(const bf16x8*)(w0p + c * 512 + nl * 32 + quad * 8);
    float4 bb = *(const float4*)(b0 + quad * 4);
    float4 bbs = make_float4(bb.x * SACT, bb.y * SACT, bb.z * SACT, bb.w * SACT);
#pragma unroll 1
    for (int i = 0; i < 9; ++i) {
        int mt = wave + 4 * i;                 // 36 mtiles = 576 px (18r x 32)
        int p = mt * 16 + nl;
        int y = p >> 5, x = p & 31;
        f32x4 acc = (f32x4)0.f;
#pragma unroll
        for (int c = 0; c < 4; ++c) {
            int t0 = c * 8 + quad * 2, t1 = t0 + 1;
            if (t0 > 24) t0 = 24;
            if (t1 > 24) t1 = 24;              // padded taps; weights zero
            int dy0 = t0 / 5, dx0 = t0 - 5 * dy0;
            int dy1 = t1 / 5, dx1 = t1 - 5 * dy1;
            uint2 lo = *(const uint2*)(s_in + ((y + dy0) * 36 + x + dx0) * 4);
            uint2 hi = *(const uint2*)(s_in + ((y + dy1) * 36 + x + dx1) * 4);
            bf16x8 a;
            ((uint2*)&a)[0] = lo; ((uint2*)&a)[1] = hi;
            acc = __builtin_amdgcn_mfma_f32_16x16x32_bf16(wf[c], a, acc, 0, 0, 0);
        }
        bool oob = ((unsigned)(oy - 8 + y + yoff) >= 128u) || ((unsigned)(ox - 8 + x) >= 128u);
        *(unsigned int*)(s0 + sw8(p * 16 + quad * 4)) = quant4(acc, bbs, SACT, oob);
    }
}

// ---------------------------------------------------------------------------
// conv1 half-slab, FP8: in s0 (18r x 32, 16B rows), out s1 fp8 16B rows.
// Paired-tap (K=32 = 2 taps x 16ch), NT=1, NPXL=392.
// ---------------------------------------------------------------------------
__device__ __forceinline__ void conv1_fp8(
    const unsigned char* __restrict__ s0, unsigned char* __restrict__ s1,
    const unsigned char* __restrict__ wB, const float* __restrict__ b1,
    int POFF, int gy0, int gx0, int wave, int lane)
{
    const int nl = lane & 15, quad = lane >> 4;
    const int h = quad >> 1, g8 = (quad & 1) * 8;

    int abase[7];
#pragma unroll
    for (int i = 0; i < 7; ++i) {
        int p = (wave + 4 * i) * 16 + nl;
        if (p > 391) p = 391;
        int y = p / 28, x = p - y * 28;
        abase[i] = (y * 32 + x) * 16 + g8;
    }
    f32x4 acc[7];
#pragma unroll
    for (int i = 0; i < 7; ++i) acc[i] = (f32x4)0.f;

    const unsigned char* wp = wB + 12288 + nl * 32 + quad * 8;

#pragma unroll 1
    for (int c0 = 0; c0 < 13; c0 += 5) {
        long wl[5];
#pragma unroll
        for (int tp = 0; tp < 5; ++tp)
            if (c0 + tp < 13) wl[tp] = *(const long*)(wp + (c0 + tp) * 512);
#pragma unroll
        for (int tp = 0; tp < 5; ++tp) {
            if (c0 + tp < 13) {
                int t = 2 * (c0 + tp) + h;
                if (t > 24) t = 24;            // padded half; weights zero
                int dy = t / 5, dx = t - 5 * dy;
                int toff = (dy * 32 + dx) * 16;
#pragma unroll
                for (int i = 0; i < 7; ++i)
                    if (wave + 4 * i < 25) {
                        long a = *(const long*)(s0 + sw8(abase[i] + toff));
                        acc[i] = __builtin_amdgcn_mfma_f32_16x16x32_fp8_fp8(wl[tp], a, acc[i], 0, 0, 0);
                    }
            }
        }
    }

    float4 bb = *(const float4*)(b1 + quad * 4);
    float4 bbs = make_float4(bb.x * SACT, bb.y * SACT, bb.z * SACT, bb.w * SACT);
#pragma unroll
    for (int i = 0; i < 7; ++i) {
        int p = (wave + 4 * i) * 16 + nl;
        if (p < 392) {
            int pg = p + POFF;
            int y = pg / 28, x = pg - y * 28;
            bool oob = ((unsigned)(gy0 + y) >= 128u) || ((unsigned)(gx0 + x) >= 128u);
            *(unsigned int*)(s1 + sw8(pg * 16 + quad * 4)) = quant4(acc[i], bbs, SREQ, oob);
        }
    }
}

// ---------------------------------------------------------------------------
// conv2: fp8 paired-tap (CIN=16), NT=2, two m-passes (I0/NI) to bound regs.
// in s1 [784][16B] sw8, out s2 [576][32B] sw32, fp8 x64.
// ---------------------------------------------------------------------------
template<int I0, int NI>
__device__ __forceinline__ void conv2_fp8(
    const unsigned char* __restrict__ s1, unsigned char* __restrict__ s2,
    const unsigned char* __restrict__ wA, const float* __restrict__ b2,
    int gy0, int gx0, int wave, int lane)
{
    const int nl = lane & 15, quad = lane >> 4;
    const int h = quad >> 1, g8 = (quad & 1) * 8;

    int abase[NI];
#pragma unroll
    for (int i = 0; i < NI; ++i) {
        int p = (wave + 4 * (I0 + i)) * 16 + nl;
        int y = p / 24, x = p - y * 24;
        abase[i] = (y * 28 + x) * 16 + g8;
    }
    f32x4 acc[NI][2];
#pragma unroll
    for (int i = 0; i < NI; ++i) { acc[i][0] = (f32x4)0.f; acc[i][1] = (f32x4)0.f; }

    const unsigned char* wp = wA + nl * 32 + quad * 8;

#pragma unroll 1
    for (int c0 = 0; c0 < 13; c0 += 3) {
        long wl[3][2];
#pragma unroll
        for (int tp = 0; tp < 3; ++tp)
            if (c0 + tp < 13) {
                wl[tp][0] = *(const long*)(wp + ((c0 + tp) * 2 + 0) * 512);
                wl[tp][1] = *(const long*)(wp + ((c0 + tp) * 2 + 1) * 512);
            }
#pragma unroll
        for (int tp = 0; tp < 3; ++tp) {
            if (c0 + tp < 13) {
                int t = 2 * (c0 + tp) + h;
                if (t > 24) t = 24;
                int dy = t / 5, dx = t - 5 * dy;
                int toff = (dy * 28 + dx) * 16;
#pragma unroll
                for (int i = 0; i < NI; ++i) {
                    long a = *(const long*)(s1 + sw8(abase[i] + toff));
                    acc[i][0] = __builtin_amdgcn_mfma_f32_16x16x32_fp8_fp8(wl[tp][0], a, acc[i][0], 0, 0, 0);
                    acc[i][1] = __builtin_amdgcn_mfma_f32_16x16x32_fp8_fp8(wl[tp][1], a, acc[i][1], 0, 0, 0);
                }
            }
        }
    }

#pragma unroll
    for (int i = 0; i < NI; ++i) {
        int p = (wave + 4 * (I0 + i)) * 16 + nl;
        int y = p / 24, x = p - y * 24;
        bool oob = ((unsigned)(gy0 + y) >= 128u) || ((unsigned)(gx0 + x) >= 128u);
#pragma unroll
        for (int nt = 0; nt < 2; ++nt) {
            float4 bb = *(const float4*)(b2 + nt * 16 + quad * 4);
            float4 bbs = make_float4(bb.x * SACT, bb.y * SACT, bb.z * SACT, bb.w * SACT);
            *(unsigned int*)(s2 + sw32(p * 32 + nt * 16 + quad * 4)) =
                quant4(acc[i][nt], bbs, SREQ, oob);
        }
    }
}

// ---------------------------------------------------------------------------
// conv3/conv4: fp8 25-tap (CIN=32, K=32=ic), NT=2, chunk CH.
// FP8OUT: fp8 x64 to 32B rows (sw32); else bf16 to 64B rows (sw48).
// ---------------------------------------------------------------------------
template<int SIN, int SOUT, int MAXM, bool GUARD, bool FP8OUT, int CH>
__device__ __forceinline__ void conv_c32_fp8(
    const unsigned char* __restrict__ sinB, unsigned char* __restrict__ soutB,
    const unsigned char* __restrict__ wA, const float* __restrict__ bias,
    int gy0, int gx0, int wave, int lane)
{
    constexpr int NM = (SOUT * SOUT) / 16;
    const int nl = lane & 15, quad = lane >> 4;

    int abase[MAXM];
#pragma unroll
    for (int i = 0; i < MAXM; ++i) {
        int p = (wave + 4 * i) * 16 + nl;
        if (GUARD && p > SOUT * SOUT - 1) p = SOUT * SOUT - 1;
        int y = p / SOUT, x = p - y * SOUT;
        abase[i] = (y * SIN + x) * 32 + quad * 8;
    }
    f32x4 acc[MAXM][2];
#pragma unroll
    for (int i = 0; i < MAXM; ++i) { acc[i][0] = (f32x4)0.f; acc[i][1] = (f32x4)0.f; }

    const unsigned char* wp = wA + nl * 32 + quad * 8;

#pragma unroll 1
    for (int c0 = 0; c0 < 25; c0 += CH) {
        long wl[CH][2];
#pragma unroll
        for (int tp = 0; tp < CH; ++tp)
            if (c0 + tp < 25) {
                wl[tp][0] = *(const long*)(wp + ((c0 + tp) * 2 + 0) * 512);
                wl[tp][1] = *(const long*)(wp + ((c0 + tp) * 2 + 1) * 512);
            }
#pragma unroll
        for (int tp = 0; tp < CH; ++tp) {
            if (c0 + tp < 25) {
                int t = c0 + tp;
                int dy = t / 5, dx = t - 5 * dy;
                int toff = (dy * SIN + dx) * 32;
#pragma unroll
                for (int i = 0; i < MAXM; ++i)
                    if (!GUARD || wave + 4 * i < NM) {
                        long a = *(const long*)(sinB + sw32(abase[i] + toff));
                        acc[i][0] = __builtin_amdgcn_mfma_f32_16x16x32_fp8_fp8(wl[tp][0], a, acc[i][0], 0, 0, 0);
                        acc[i][1] = __builtin_amdgcn_mfma_f32_16x16x32_fp8_fp8(wl[tp][1], a, acc[i][1], 0, 0, 0);
                    }
            }
        }
    }

#pragma unroll
    for (int i = 0; i < MAXM; ++i) {
        int p = (wave + 4 * i) * 16 + nl;
        if (!GUARD || p < SOUT * SOUT) {
            int y = p / SOUT, x = p - y * SOUT;
            bool oob = ((unsigned)(gy0 + y) >= 128u) || ((unsigned)(gx0 + x) >= 128u);
#pragma unroll
            for (int nt = 0; nt < 2; ++nt) {
                float4 bb = *(const float4*)(bias + nt * 16 + quad * 4);
                if (FP8OUT) {
                    float4 bbs = make_float4(bb.x * SACT, bb.y * SACT, bb.z * SACT, bb.w * SACT);
                    *(unsigned int*)(soutB + sw32(p * 32 + nt * 16 + quad * 4)) =
                        quant4(acc[i][nt], bbs, SREQ, oob);
                } else {
                    f32x4 s;
                    s[0] = acc[i][nt][0] * SINV; s[1] = acc[i][nt][1] * SINV;
                    s[2] = acc[i][nt][2] * SINV; s[3] = acc[i][nt][3] * SINV;
                    store_relu4(soutB + sw48(p * 64 + nt * 32 + quad * 8), s, bb, oob);
                }
            }
        }
    }
}

// ---------------------------------------------------------------------------
// Fused pipeline: 256 threads = one 16x16 output tile. LDS 31232 B:
//   s1 @0 12544 | s3 @0 12800 | sin @12800 6336 | s0 @19136 9216
//   s2 @12800 18432 | s4 @12800 16384   (ping-pong, liveness-checked)
// ---------------------------------------------------------------------------
extern "C" __global__ void __launch_bounds__(256, 3)
gnn_paf_mfma(const float* __restrict__ cnn, const unsigned char* __restrict__ wB,
             const float* __restrict__ b0, const float* __restrict__ b1,
             const float* __restrict__ b2, const float* __restrict__ b3,
             const float* __restrict__ b4, const float* __restrict__ b5,
             const float* __restrict__ w6, const float* __restrict__ b6,
             float* __restrict__ out)
{
    __shared__ __align__(64) unsigned char smem[31232];
    unsigned char*  const s1   = smem;                             // 12544
    unsigned char*  const s3   = smem;                             // 12800
    unsigned short* const sin_ = (unsigned short*)(smem + 12800);  // 6336
    unsigned char*  const s0   = smem + 19136;                     // 9216
    unsigned char*  const s2   = smem + 12800;                     // 18432
    unsigned char*  const s4   = smem + 12800;                     // 16384

    const int tid  = threadIdx.x;
    const int lane = tid & 63, wave = tid >> 6;       // 4 waves
    const int tile = blockIdx.x, img = blockIdx.y;
    const int oy = (tile >> 3) * 16, ox = (tile & 7) * 16;
    const int n = img / 19, g = img - n * 19;
    const int ch0 = EDGE_A[g], ch1 = EDGE_B[g], ch2 = 19 + 2 * g, ch3 = 20 + 2 * g;
    const int nl = lane & 15, quad = lane >> 4;
    const long long nb = (long long)n * 57 * 16384;

    // ---- gatherA: halo rows 0..21 -> sin_ (22x36x4 bf16, zero-padded)
    for (int idx = tid; idx < 792; idx += 256) {
        int r = idx / 36, c = idx - r * 36;
        int gy = oy - 10 + r, gx = ox - 10 + c;
        float v0 = 0.f, v1 = 0.f, v2 = 0.f, v3 = 0.f;
        if ((unsigned)gy < 128u && (unsigned)gx < 128u) {
            int off = gy * 128 + gx;
            v0 = cnn[nb + (long long)ch0 * 16384 + off];
            v1 = cnn[nb + (long long)ch1 * 16384 + off];
            v2 = cnn[nb + (long long)ch2 * 16384 + off];
            v3 = cnn[nb + (long long)ch3 * 16384 + off];
        }
        uint2 v; v.x = pack2(v0, v1); v.y = pack2(v2, v3);
        *(uint2*)(sin_ + idx * 4) = v;
    }
    __syncthreads();

    conv0_slab(sin_, s0, wB, b0, 0, oy, ox, wave, lane);       // s0 rows 0..17
    __syncthreads();

    // gatherB loads (input rows 14..35) pipelined across conv1a
    float gv[4][4];
#pragma unroll
    for (int j = 0; j < 4; ++j) {
        gv[j][0] = gv[j][1] = gv[j][2] = gv[j][3] = 0.f;
        int idx = tid + 256 * j;
        if (idx < 792) {
            int r = idx / 36, c = idx - r * 36;
            int gy = oy + 4 + r, gx = ox - 10 + c;
            if ((unsigned)gy < 128u && (unsigned)gx < 128u) {
                int off = gy * 128 + gx;
                gv[j][0] = cnn[nb + (long long)ch0 * 16384 + off];
                gv[j][1] = cnn[nb + (long long)ch1 * 16384 + off];
                gv[j][2] = cnn[nb + (long long)ch2 * 16384 + off];
                gv[j][3] = cnn[nb + (long long)ch3 * 16384 + off];
            }
        }
    }
    conv1_fp8(s0, s1, wB, b1, 0, oy - 6, ox - 6, wave, lane);
#pragma unroll
    for (int j = 0; j < 4; ++j) {
        int idx = tid + 256 * j;
        if (idx < 792) {
            uint2 v; v.x = pack2(gv[j][0], gv[j][1]); v.y = pack2(gv[j][2], gv[j][3]);
            *(uint2*)(sin_ + idx * 4) = v;
        }
    }
    __syncthreads();

    conv0_slab(sin_, s0, wB, b0, 14, oy, ox, wave, lane);      // s0 rows 14..31
    __syncthreads();

    conv1_fp8(s0, s1, wB, b1, 392, oy - 6, ox - 6, wave, lane);
    __syncthreads();

    conv2_fp8<0, 5>(s1, s2, wB + 18944, b2, oy - 4, ox - 4, wave, lane);
    conv2_fp8<5, 4>(s1, s2, wB + 18944, b2, oy - 4, ox - 4, wave, lane);
    __syncthreads();

    conv_c32_fp8<24, 20, 7, true,  true,  3>(s2, s3, wB + 32256, b3, oy - 2, ox - 2, wave, lane);
    __syncthreads();

    conv_c32_fp8<20, 16, 4, false, false, 5>(s3, s4, wB + 57856, b4, oy, ox, wave, lane);
    __syncthreads();

    // ---- conv5 (1x1 32->128) bf16 + relu + conv6 (128->2)
    {
        const unsigned short* w5p = (const unsigned short*)wB;
        bf16x8 w5f[8];
#pragma unroll
        for (int nt = 0; nt < 8; ++nt)
            w5f[nt] = *(const bf16x8*)(w5p + nt * 512 + nl * 32 + quad * 8);
        const float b6q = b6[quad & 1];
#pragma unroll 1
        for (int ii = 0; ii < 4; ++ii) {
            int mt = wave + 4 * ii;                // 16 mtiles
            int lin = (mt * 16 + nl) * 64 + quad * 16;
            bf16x8 pf = *(const bf16x8*)(s4 + sw48(lin));
            float o0 = 0.f, o1 = 0.f;
#pragma unroll
            for (int nt = 0; nt < 8; ++nt) {
                f32x4 acc = (f32x4)0.f;
                acc = __builtin_amdgcn_mfma_f32_16x16x32_bf16(w5f[nt], pf, acc, 0, 0, 0);
                float4 bb  = *(const float4*)(b5 + nt * 16 + quad * 4);
                float4 wa  = *(const float4*)(w6 + nt * 16 + quad * 4);
                float4 wb2 = *(const float4*)(w6 + 128 + nt * 16 + quad * 4);
                float h0 = fmaxf(acc[0] + bb.x, 0.f), h1 = fmaxf(acc[1] + bb.y, 0.f);
                float h2 = fmaxf(acc[2] + bb.z, 0.f), h3 = fmaxf(acc[3] + bb.w, 0.f);
                o0 = fmaf(h0, wa.x, fmaf(h1, wa.y, fmaf(h2, wa.z, fmaf(h3, wa.w, o0))));
                o1 = fmaf(h0, wb2.x, fmaf(h1, wb2.y, fmaf(h2, wb2.z, fmaf(h3, wb2.w, o1))));
            }
            o0 += __shfl_xor(o0, 16, 64); o0 += __shfl_xor(o0, 32, 64);
            o1 += __shfl_xor(o1, 16, 64); o1 += __shfl_xor(o1, 32, 64);
            if (quad < 2) {
                float val = ((quad == 0) ? o0 : o1) + b6q;
                long long ob = (((long long)n * 38 + 2 * g + quad) * 128 + (oy + mt)) * 128 + (ox + nl);
                out[ob] = val;
            }
        }
    }
}

extern "C" void kernel_launch(void* const* d_in, const int* in_sizes, int n_in,
                              void* d_out, int out_size, void* d_ws, size_t ws_size,
                              hipStream_t stream) {
    const float* cnn = (const float*)d_in[0];
    const float* w0 = (const float*)d_in[2];  const float* b0 = (const float*)d_in[3];
    const float* w1 = (const float*)d_in[4];  const float* b1 = (const float*)d_in[5];
    const float* w2 = (const float*)d_in[6];  const float* b2 = (const float*)d_in[7];
    const float* w3 = (const float*)d_in[8];  const float* b3 = (const float*)d_in[9];
    const float* w4 = (const float*)d_in[10]; const float* b4 = (const float*)d_in[11];
    const float* w5 = (const float*)d_in[12]; const float* b5 = (const float*)d_in[13];
    const float* w6 = (const float*)d_in[14]; const float* b6 = (const float*)d_in[15];
    float* out = (float*)d_out;
    unsigned char* wB = (unsigned char*)d_ws;   // 83456 B used

    hipLaunchKernelGGL(reorder_weights, dim3(278), dim3(256), 0, stream,
                       w0, w1, w2, w3, w4, w5, wB);
    hipLaunchKernelGGL(gnn_paf_mfma, dim3(64, 304), dim3(256), 0, stream,
                       cnn, wB, b0, b1, b2, b3, b4, b5, w6, b6, out);
}